// Round 7
// baseline (695.893 us; speedup 1.0000x reference)
//
#include <hip/hip_runtime.h>
#include <hip/hip_bf16.h>
#include <math.h>

typedef __bf16 bf16;
typedef __attribute__((ext_vector_type(4))) __bf16 bf16x4;
typedef __attribute__((ext_vector_type(8))) __bf16 bf16x8;
typedef __attribute__((ext_vector_type(4))) float f32x4;

#define N_NODES 20000
#define N_EDGES 320000
#define E2 (N_EDGES + N_NODES)   // 340000 edges incl self-loops
#define F_IN 50
#define D1 1024                  // H1*C1
#define NP12 2048                // padded GEMM out-cols, layer 2 ([W|Wl])
#define NP3 1024                 // padded GEMM out-cols, layer 3 (847 -> 1024, 256-tile)
#define SG 2048                  // row stride of GEMM output buffer
#define KA 320                   // layer-1 fused K: 4*64 aggx + 64 x

// params pool element offsets (bf16 pool)
#define PO_A1S 0
#define PO_A1D 1024
#define PO_B1  2048
#define PO_BL1 3072
#define PO_A2S 4096
#define PO_A2D 5120
#define PO_B2  6144
#define PO_BL2 7168
#define PO_A3S 8192
#define PO_A3D 8918
#define PO_B3  9644
#define PO_BL3 9765
#define PO_END 9886

// k_prep block-range sizes
#define PB_PADX  5000            // N_NODES*64/256
#define PB_WF1   1280            // D1*KA/256
#define PB_PAR   39              // ceil(PO_END/256)
#define PB_LOG1  5000            // N_NODES/4

__device__ __forceinline__ int clampi(int v, int lo, int hi)
{
    return v < lo ? lo : (v > hi ? hi : v);
}

__device__ __forceinline__ float loadf(const void* p, long idx, int isb)
{
    return isb ? (float)((const bf16*)p)[idx] : ((const float*)p)[idx];
}

__device__ __forceinline__ int loadei(const int* ei, long idx, int i64)
{
    return i64 ? ei[2 * idx] : ei[idx];
}

// --------------------------------------------------------------- detect -----
__global__ void k_detect(const int* __restrict__ ei,
                         const unsigned short* __restrict__ xw,
                         int* __restrict__ flags)
{
    if (blockIdx.x != 0 || threadIdx.x != 0) return;
    int allz = 1;
    for (int i = 0; i < 128; ++i)
        if (ei[2 * i + 1] != 0) { allz = 0; break; }
    int inr = 0;
    for (int i = 0; i < 128; ++i) {
        int e = (xw[2 * i] >> 7) & 0xFF;
        if (e >= 100 && e <= 140) inr++;
    }
    flags[0] = allz;
    flags[1] = (inr >= 64) ? 1 : 0;
}

// ---------------------------------------------------------------- GEMM ------
// m97-style 128x128 tile (layer 1: K=320). BACT: fused bias+ELU epilogue.
template <bool BACT>
__global__ __launch_bounds__(256) void k_gemm(const bf16* __restrict__ A,
                                              const bf16* __restrict__ Bt,
                                              bf16* __restrict__ C,
                                              int M, int K, int lda, int ldb, int ldc,
                                              int mtiles, int ntiles,
                                              const bf16* __restrict__ bias)
{
    __shared__ bf16 As[128 * 64];
    __shared__ bf16 Bs[128 * 64];

    int id = blockIdx.x;
    int gfull = mtiles >> 3;
    int base  = gfull * 8 * ntiles;
    int x, y;
    if (id < base) {
        int gsz = 8 * ntiles;
        int g = id / gsz;
        int r = id - g * gsz;
        x = g * 8 + (r & 7);
        y = r >> 3;
    } else {
        int rem = mtiles - (gfull << 3);
        int r = id - base;
        x = (gfull << 3) + r % rem;
        y = r / rem;
    }
    const int m0 = x * 128;
    const int n0 = y * 128;

    const int tid  = threadIdx.x;
    const int wave = tid >> 6;
    const int lane = tid & 63;
    const int wm   = (wave >> 1) * 64;
    const int wn   = (wave & 1) * 64;
    const int frow  = lane & 15;

    const int srow = wave * 32 + (lane >> 3);
    const int scol = (((lane & 7) ^ (lane >> 3)) * 8);

    f32x4 acc[4][4];
#pragma unroll
    for (int i = 0; i < 4; ++i)
#pragma unroll
        for (int j = 0; j < 4; ++j)
#pragma unroll
            for (int r = 0; r < 4; ++r) acc[i][j][r] = 0.f;

    for (int k0 = 0; k0 < K; k0 += 64) {
#pragma unroll
        for (int i = 0; i < 4; ++i) {
            int ra = srow + i * 8;
            int ga = m0 + ra; if (ga > M - 1) ga = M - 1;   // junk rows -> discarded C rows
            __builtin_amdgcn_global_load_lds(
                (const __attribute__((address_space(1))) void*)(A + (size_t)ga * lda + k0 + scol),
                (__attribute__((address_space(3))) void*)(As + wave * 2048 + i * 512),
                16, 0, 0);
            int gb = n0 + ra;
            __builtin_amdgcn_global_load_lds(
                (const __attribute__((address_space(1))) void*)(Bt + (size_t)gb * ldb + k0 + scol),
                (__attribute__((address_space(3))) void*)(Bs + wave * 2048 + i * 512),
                16, 0, 0);
        }
        __syncthreads();
#pragma unroll
        for (int kk = 0; kk < 2; ++kk) {
            const int coff = (((kk * 4 + (lane >> 4)) ^ (frow & 7)) << 3);
            bf16x8 af[4], bfr[4];
#pragma unroll
            for (int i = 0; i < 4; ++i) {
                af[i]  = *(const bf16x8*)(As + (wm + i * 16 + frow) * 64 + coff);
                bfr[i] = *(const bf16x8*)(Bs + (wn + i * 16 + frow) * 64 + coff);
            }
#pragma unroll
            for (int i = 0; i < 4; ++i)
#pragma unroll
                for (int j = 0; j < 4; ++j)
                    acc[i][j] = __builtin_amdgcn_mfma_f32_16x16x32_bf16(af[i], bfr[j], acc[i][j], 0, 0, 0);
        }
        __syncthreads();
    }

#pragma unroll
    for (int i = 0; i < 4; ++i) {
#pragma unroll
        for (int j = 0; j < 4; ++j) {
            int rbase = m0 + wm + i * 16 + (lane >> 4) * 4;
            int col   = n0 + wn + j * 16 + frow;
            if constexpr (BACT) {
                float bv = (float)bias[col];
#pragma unroll
                for (int r = 0; r < 4; ++r) {
                    int row = rbase + r;
                    if (row < M) {
                        float v = acc[i][j][r] + bv;
                        v = (v > 0.f) ? v : (__expf(v) - 1.f);
                        C[(size_t)row * ldc + col] = (bf16)v;
                    }
                }
            } else {
#pragma unroll
                for (int r = 0; r < 4; ++r) {
                    int row = rbase + r;
                    if (row < M) C[(size_t)row * ldc + col] = (bf16)acc[i][j][r];
                }
            }
        }
    }
}

// ------------------------------------------------- 256x256 8-phase GEMM v2 --
// Corrected mapping: phase (MH,NH) reads ONLY A-half MH and B-half NH.
//   wave wr=wave>>2 picks 64-row slice INSIDE each 128-row half,
//   wave wc=wave&3 picks 32-col slice INSIDE each 128-col half.
// Stage order per tile (for t+1): A-lo @ph0, B-lo @ph1, B-hi @ph2, A-hi @ph3.
// FIFO waits (2 loads/half/wave, 3 halves in flight): vmcnt(6) @ph0/1/2,
// no wait @ph3; epilogue drains 4->2->0. Never vmcnt(0) in main loop.
// Cross-checks: ph0 barrier = tile rendezvous (covers Blo(t+2) WAR);
// ph3's concurrent Alo(t+2)/Ahi(t+1) stage regions disjoint from its reads.
__global__ __launch_bounds__(512, 2) void k_gemm256(const bf16* __restrict__ A,
                                                    const bf16* __restrict__ Bt,
                                                    bf16* __restrict__ C,
                                                    int M, int K, int lda, int ldb, int ldc,
                                                    int mtiles, int ntiles)
{
    __shared__ bf16 As[2][256 * 64];
    __shared__ bf16 Bs[2][256 * 64];

    int id = blockIdx.x;
    int gfull = mtiles >> 3;
    int base  = gfull * 8 * ntiles;
    int x, y;
    if (id < base) {
        int gsz = 8 * ntiles;
        int g = id / gsz;
        int r = id - g * gsz;
        x = g * 8 + (r & 7);
        y = r >> 3;
    } else {
        int rem = mtiles - (gfull << 3);
        int r = id - base;
        x = (gfull << 3) + r % rem;
        y = r / rem;
    }
    const int m0 = x * 256;
    const int n0 = y * 256;

    const int tid  = threadIdx.x;
    const int wave = tid >> 6;
    const int lane = tid & 63;
    const int wr   = wave >> 2;        // 0..1: 64-row slice within each A-half
    const int wc   = wave & 3;         // 0..3: 32-col slice within each B-half
    const int frow = lane & 15;
    const int hi   = lane >> 4;        // 0..3
    const int sr8  = lane >> 3;        // 0..7
    const int scol = (((lane & 7) ^ sr8) << 3);

    // one stage half = 128 rows (2 global_load_lds per wave, 8 waves)
    auto stage_a = [&](int b, int h, int t1) {
        const int k0s = t1 << 6;
#pragma unroll
        for (int i_ = 0; i_ < 2; ++i_) {
            int row_ = h * 128 + i_ * 64 + wave * 8 + sr8;
            int ga_ = m0 + row_; if (ga_ > M - 1) ga_ = M - 1;
            __builtin_amdgcn_global_load_lds(
                (const __attribute__((address_space(1))) void*)(A + (size_t)ga_ * lda + k0s + scol),
                (__attribute__((address_space(3))) void*)(&As[b][(h * 128 + i_ * 64 + wave * 8) * 64]),
                16, 0, 0);
        }
    };
    auto stage_b = [&](int b, int h, int t1) {
        const int k0s = t1 << 6;
#pragma unroll
        for (int i_ = 0; i_ < 2; ++i_) {
            int row_ = h * 128 + i_ * 64 + wave * 8 + sr8;
            int gb_ = n0 + row_;
            __builtin_amdgcn_global_load_lds(
                (const __attribute__((address_space(1))) void*)(Bt + (size_t)gb_ * ldb + k0s + scol),
                (__attribute__((address_space(3))) void*)(&Bs[b][(h * 128 + i_ * 64 + wave * 8) * 64]),
                16, 0, 0);
        }
    };

    f32x4 acc[8][4];
#pragma unroll
    for (int i = 0; i < 8; ++i)
#pragma unroll
        for (int j = 0; j < 4; ++j)
#pragma unroll
            for (int r = 0; r < 4; ++r) acc[i][j][r] = 0.f;

    // compute quadrant (MH,NH): reads A rows MH*128+wr*64+[0,64), B rows NH*128+wc*32+[0,32)
    auto compute = [&](int b, int MH, int NH) {
        bf16x8 af[4][2], bv[2][2];
#pragma unroll
        for (int m_ = 0; m_ < 4; ++m_)
#pragma unroll
            for (int kk_ = 0; kk_ < 2; ++kk_)
                af[m_][kk_] = *(const bf16x8*)&As[b][
                    (MH * 128 + wr * 64 + m_ * 16 + frow) * 64 +
                    (((kk_ * 4 + hi) ^ (frow & 7)) << 3)];
#pragma unroll
        for (int n_ = 0; n_ < 2; ++n_)
#pragma unroll
            for (int kk_ = 0; kk_ < 2; ++kk_)
                bv[n_][kk_] = *(const bf16x8*)&Bs[b][
                    (NH * 128 + wc * 32 + n_ * 16 + frow) * 64 +
                    (((kk_ * 4 + hi) ^ (frow & 7)) << 3)];
        __builtin_amdgcn_s_setprio(1);
#pragma unroll
        for (int kk_ = 0; kk_ < 2; ++kk_)
#pragma unroll
            for (int m_ = 0; m_ < 4; ++m_)
#pragma unroll
                for (int n_ = 0; n_ < 2; ++n_)
                    acc[MH * 4 + m_][NH * 2 + n_] =
                        __builtin_amdgcn_mfma_f32_16x16x32_bf16(
                            af[m_][kk_], bv[n_][kk_],
                            acc[MH * 4 + m_][NH * 2 + n_], 0, 0, 0);
        __builtin_amdgcn_s_setprio(0);
    };

    // prologue: stage tile 0 fully into buf 0 (FIFO order)
    stage_a(0, 0, 0);
    stage_b(0, 0, 0);
    stage_b(0, 1, 0);
    stage_a(0, 1, 0);

    const int nt = K >> 6;
    int p = 0;
#pragma unroll 1
    for (int t = 0; t < nt - 1; ++t, p ^= 1) {
        // ph0: needs A-lo(t),B-lo(t)
        stage_a(p ^ 1, 0, t + 1);
        asm volatile("s_waitcnt vmcnt(6)" ::: "memory");
        __builtin_amdgcn_s_barrier();
        compute(p, 0, 0);
        // ph1: needs B-hi(t)
        stage_b(p ^ 1, 0, t + 1);
        asm volatile("s_waitcnt vmcnt(6)" ::: "memory");
        __builtin_amdgcn_s_barrier();
        compute(p, 0, 1);
        // ph2: needs A-hi(t)
        stage_b(p ^ 1, 1, t + 1);
        asm volatile("s_waitcnt vmcnt(6)" ::: "memory");
        __builtin_amdgcn_s_barrier();
        compute(p, 1, 1);
        // ph3: all halves of t already drained
        stage_a(p ^ 1, 1, t + 1);
        compute(p, 1, 0);
    }
    // epilogue tile: no staging; drain 4 -> 2 -> 0
    asm volatile("s_waitcnt vmcnt(4)" ::: "memory");
    __builtin_amdgcn_s_barrier();
    compute(p, 0, 0);
    asm volatile("s_waitcnt vmcnt(2)" ::: "memory");
    __builtin_amdgcn_s_barrier();
    compute(p, 0, 1);
    asm volatile("s_waitcnt vmcnt(0)" ::: "memory");
    __builtin_amdgcn_s_barrier();
    compute(p, 1, 1);
    compute(p, 1, 0);

#pragma unroll
    for (int mf = 0; mf < 8; ++mf) {
#pragma unroll
        for (int nf = 0; nf < 4; ++nf) {
            int row0 = m0 + (mf >> 2) * 128 + wr * 64 + (mf & 3) * 16 + hi * 4;
            int col  = n0 + (nf >> 1) * 128 + wc * 32 + (nf & 1) * 16 + frow;
#pragma unroll
            for (int r = 0; r < 4; ++r) {
                int row = row0 + r;
                if (row < M) C[(size_t)row * ldc + col] = (bf16)acc[mf][nf][r];
            }
        }
    }
}

// ------------------------------------------------------------ prep kernels --
// ws[k][h] = sum_c W1[k, h*256+c]*a1s[h,c]; wd likewise; bsum = b1+bl1.
__global__ __launch_bounds__(256) void k_veca(const void* __restrict__ W1,
                                              const void* __restrict__ a1s,
                                              const void* __restrict__ a1d,
                                              const void* __restrict__ b1,
                                              const void* __restrict__ bl1,
                                              float* __restrict__ ws, float* __restrict__ wd,
                                              bf16* __restrict__ bsum,
                                              const int* __restrict__ flags)
{
    const int isb = flags[1];
    const int k = blockIdx.x;          // 0..63
    const int h = threadIdx.x >> 6;
    const int c0 = threadIdx.x & 63;
    float s = 0.f, d = 0.f;
    if (k < F_IN) {
        for (int c = c0; c < 256; c += 64) {
            float wv = loadf(W1, (long)k * D1 + h * 256 + c, isb);
            s += wv * loadf(a1s, h * 256 + c, isb);
            d += wv * loadf(a1d, h * 256 + c, isb);
        }
    }
#pragma unroll
    for (int off = 32; off; off >>= 1) {
        s += __shfl_xor(s, off);
        d += __shfl_xor(d, off);
    }
    if (c0 == 0) { ws[k * 4 + h] = s; wd[k * 4 + h] = d; }
    if (k < 4) {
        int j = k * 256 + threadIdx.x;
        bsum[j] = (bf16)(loadf(b1, j, isb) + loadf(bl1, j, isb));
    }
}

struct P12 { const void* s[12]; };

// merged prep: padx | wfuse1 | params | logits1-from-x, block-range dispatch.
__global__ __launch_bounds__(256) void k_prep(const void* __restrict__ x,
                                              const void* __restrict__ W1,
                                              const void* __restrict__ Wl1,
                                              P12 ps,
                                              bf16* __restrict__ A2,
                                              bf16* __restrict__ Bt,
                                              bf16* __restrict__ pool,
                                              const float* __restrict__ ws,
                                              const float* __restrict__ wd,
                                              float* __restrict__ es,
                                              float* __restrict__ ed,
                                              const int* __restrict__ flags)
{
    const int isb = flags[1];
    int b = blockIdx.x;

    if (b < PB_PADX) {                       // ---- x -> A2[n*KA + 256 + k]
        int idx = b * 256 + threadIdx.x;
        int n = idx >> 6, k = idx & 63;
        A2[(size_t)n * KA + 256 + k] = (k < F_IN) ? (bf16)loadf(x, (long)n * F_IN + k, isb)
                                                  : (bf16)0.f;
        return;
    }
    b -= PB_PADX;

    if (b < PB_WF1) {                        // ---- fused layer-1 B^T
        int idx = b * 256 + threadIdx.x;
        int j = idx / KA;
        int kp = idx - j * KA;
        float v = 0.f;
        if (kp < 256) {
            int hp = kp >> 6, k = kp & 63;
            if ((j >> 8) == hp && k < F_IN) v = loadf(W1, (long)k * D1 + j, isb);
        } else {
            int k = kp - 256;
            if (k < F_IN) v = loadf(Wl1, (long)k * D1 + j, isb);
        }
        Bt[idx] = (bf16)v;
        return;
    }
    b -= PB_WF1;

    if (b < PB_PAR) {                        // ---- params pool
        const int off[13] = {PO_A1S, PO_A1D, PO_B1, PO_BL1, PO_A2S, PO_A2D, PO_B2,
                             PO_BL2, PO_A3S, PO_A3D, PO_B3, PO_BL3, PO_END};
        int idx = b * 256 + threadIdx.x;
        if (idx < PO_END) {
            int seg = 0;
            while (idx >= off[seg + 1]) seg++;
            pool[idx] = (bf16)loadf(ps.s[seg], idx - off[seg], isb);
        }
        return;
    }
    b -= PB_PAR;

    // ---- layer-1 logits from x (wave per node)
    const int wave = threadIdx.x >> 6;
    const int lane = threadIdx.x & 63;
    const int n = b * 4 + wave;
    if (n >= N_NODES) return;
    float xv = (lane < F_IN) ? loadf(x, (long)n * F_IN + lane, isb) : 0.f;
    f32x4 wsv = *(const f32x4*)(ws + lane * 4);
    f32x4 wdv = *(const f32x4*)(wd + lane * 4);
    float s[4], d[4];
#pragma unroll
    for (int h = 0; h < 4; ++h) { s[h] = xv * wsv[h]; d[h] = xv * wdv[h]; }
#pragma unroll
    for (int off = 32; off; off >>= 1)
#pragma unroll
        for (int h = 0; h < 4; ++h) {
            s[h] += __shfl_xor(s[h], off);
            d[h] += __shfl_xor(d[h], off);
        }
    if (lane == 0) {
#pragma unroll
        for (int h = 0; h < 4; ++h) { es[n * 4 + h] = s[h]; ed[n * 4 + h] = d[h]; }
    }
}

// Tiled transpose-concat: Bt[n][k] = [Wa | Wb | 0](k, n), K=1024 rows.
__global__ __launch_bounds__(256) void k_wcatT(const void* __restrict__ Wa,
                                               const void* __restrict__ Wb,
                                               bf16* __restrict__ Bt,
                                               int split, int da, int db,
                                               const int* __restrict__ flags)
{
    __shared__ bf16 T[64][65];
    const int isb = flags[1];
    const int k0 = blockIdx.x * 64;
    const int n0 = blockIdx.y * 64;
    const int r = threadIdx.x >> 6;    // 0..3
    const int c = threadIdx.x & 63;
    const int n = n0 + c;
#pragma unroll
    for (int kk = 0; kk < 16; ++kk) {
        int k = k0 + r + kk * 4;
        float v = 0.f;
        if (n < split)           v = loadf(Wa, (long)k * da + n, isb);
        else if (n < split + db) v = loadf(Wb, (long)k * db + (n - split), isb);
        T[r + kk * 4][c] = (bf16)v;
    }
    __syncthreads();
#pragma unroll
    for (int kk = 0; kk < 16; ++kk) {
        int nn = r + kk * 4;
        Bt[(size_t)(n0 + nn) * 1024 + k0 + c] = T[c][nn];
    }
}

// ------------------------------------------------------------- CSR build ----
__global__ void k_count(const int* __restrict__ ei, int* __restrict__ cnt,
                        const int* __restrict__ flags)
{
    int e = blockIdx.x * 256 + threadIdx.x;
    if (e >= E2) return;
    int i64 = flags[0];
    int d = (e < N_EDGES) ? loadei(ei, (long)N_EDGES + e, i64) : (e - N_EDGES);
    d = clampi(d, 0, N_NODES - 1);
    atomicAdd(&cnt[d], 1);
}

__global__ __launch_bounds__(256) void k_scan(const int* __restrict__ cnt,
                                              int* __restrict__ rp,
                                              int* __restrict__ cur)
{
    __shared__ int ssum[256];
    int tid = threadIdx.x;
    const int chunk = (N_NODES + 255) / 256;
    int lo = tid * chunk;
    int hi = lo + chunk; if (hi > N_NODES) hi = N_NODES;
    int s = 0;
    for (int i = lo; i < hi; ++i) s += cnt[i];
    ssum[tid] = s;
    __syncthreads();
    if (tid == 0) {
        int run = 0;
        for (int i = 0; i < 256; ++i) { int t = ssum[i]; ssum[i] = run; run += t; }
        rp[N_NODES] = run;
    }
    __syncthreads();
    int run = ssum[tid];
    for (int i = lo; i < hi; ++i) { rp[i] = run; cur[i] = run; run += cnt[i]; }
}

__global__ void k_fill(const int* __restrict__ ei, int* __restrict__ cur,
                       int* __restrict__ ss, const int* __restrict__ flags)
{
    int e = blockIdx.x * 256 + threadIdx.x;
    if (e >= E2) return;
    int i64 = flags[0];
    int s, d;
    if (e < N_EDGES) {
        s = loadei(ei, e, i64);
        d = loadei(ei, (long)N_EDGES + e, i64);
    } else {
        s = e - N_EDGES; d = s;
    }
    s = clampi(s, 0, N_NODES - 1);
    d = clampi(d, 0, N_NODES - 1);
    int pos = atomicAdd(&cur[d], 1);
    if (pos >= 0 && pos < E2) ss[pos] = s;
}

// ----------------------------------------------------- attention kernels ----
// layer-1 aggregate: aggx[n,h,k] = sum_e alpha[e,h] x[src_e,k] (block per node)
__global__ __launch_bounds__(256) void k_aggx(bf16* __restrict__ A2,
                                              const float* __restrict__ es,
                                              const float* __restrict__ ed,
                                              const int* __restrict__ rp,
                                              const int* __restrict__ ss)
{
    __shared__ float smx[4], sinv[4], sed[4];
    __shared__ float sal[64 * 4];
    __shared__ int   ssrc[64];

    const int n   = blockIdx.x;
    const int tid = threadIdx.x;
    int r0 = clampi(rp[n], 0, E2);
    int r1 = clampi(rp[n + 1], r0, E2);
    const int deg = r1 - r0;

    const int sw = tid >> 5, ln = tid & 31;
    if (sw < 4) {
        int h = sw;
        float edn = ed[n * 4 + h];
        float mx = -1e30f;
        for (int e = ln; e < deg; e += 32) {
            int s = clampi(ss[r0 + e], 0, N_NODES - 1);
            float w = es[s * 4 + h] + edn;
            w = (w > 0.f) ? w : 0.2f * w;
            mx = fmaxf(mx, w);
        }
#pragma unroll
        for (int off = 16; off; off >>= 1) mx = fmaxf(mx, __shfl_xor(mx, off, 32));
        float sm = 0.f;
        for (int e = ln; e < deg; e += 32) {
            int s = clampi(ss[r0 + e], 0, N_NODES - 1);
            float w = es[s * 4 + h] + edn;
            w = (w > 0.f) ? w : 0.2f * w;
            sm += __expf(w - mx);
        }
#pragma unroll
        for (int off = 16; off; off >>= 1) sm += __shfl_xor(sm, off, 32);
        if (ln == 0) { smx[h] = mx; sinv[h] = 1.f / fmaxf(sm, 1e-16f); sed[h] = edn; }
    }
    __syncthreads();

    const int k  = tid & 63;
    const int hh = tid >> 6;
    float acc = 0.f;

    for (int e0 = 0; e0 < deg; e0 += 64) {
        int ce = min(64, deg - e0);
        int ce4 = (ce + 3) & ~3;
        __syncthreads();
        if (tid < ce4 * 4) {
            int e = tid >> 2, h = tid & 3;
            int valid = (e < ce);
            int s = valid ? clampi(ss[r0 + e0 + e], 0, N_NODES - 1) : 0;
            float w = es[s * 4 + h] + sed[h];
            w = (w > 0.f) ? w : 0.2f * w;
            sal[e * 4 + h] = valid ? __expf(w - smx[h]) * sinv[h] : 0.f;
            if (h == 0) ssrc[e] = s;
        }
        __syncthreads();
        for (int e = 0; e < ce4; e += 4) {
            float xv[4], al[4];
#pragma unroll
            for (int p = 0; p < 4; ++p) {
                int s = ssrc[e + p];
                xv[p] = (float)A2[(size_t)s * KA + 256 + k];
            }
#pragma unroll
            for (int p = 0; p < 4; ++p) al[p] = sal[(e + p) * 4 + hh];
#pragma unroll
            for (int p = 0; p < 4; ++p) acc += al[p] * xv[p];
        }
    }
    A2[(size_t)n * KA + hh * 64 + k] = (bf16)acc;
}

// layers 2/3 logits on h (wave per node)
template <int H, int C>
__global__ __launch_bounds__(256) void k_logits(const bf16* __restrict__ G,
                                                const bf16* __restrict__ as_,
                                                const bf16* __restrict__ ad_,
                                                float* __restrict__ es, float* __restrict__ ed)
{
    const int wave = threadIdx.x >> 6;
    const int lane = threadIdx.x & 63;
    const int n = blockIdx.x * 4 + wave;
    if (n >= N_NODES) return;

#pragma unroll
    for (int h = 0; h < H; ++h) {
        float s = 0.f, d = 0.f;
        if constexpr (C == 256) {
            bf16x4 g  = *(const bf16x4*)(G + (size_t)n * SG + h * 256 + lane * 4);
            bf16x4 av = *(const bf16x4*)(as_ + h * 256 + lane * 4);
            bf16x4 dv = *(const bf16x4*)(ad_ + h * 256 + lane * 4);
#pragma unroll
            for (int j = 0; j < 4; ++j) {
                float gv = (float)g[j];
                s += gv * (float)av[j];
                d += gv * (float)dv[j];
            }
        } else {
            for (int c = lane; c < C; c += 64) {
                float hv = (float)G[(size_t)n * SG + h * C + c];
                s += hv * (float)as_[h * C + c];
                d += hv * (float)ad_[h * C + c];
            }
        }
#pragma unroll
        for (int off = 32; off; off >>= 1) {
            s += __shfl_xor(s, off);
            d += __shfl_xor(d, off);
        }
        if (lane == 0) { es[n * H + h] = s; ed[n * H + h] = d; }
    }
}

// Fused per-dst-node softmax + gather-aggregate + bias + skip (+mean/ELU).
template <int H, int C, bool MEAN, bool ELU, bool EXTOUT>
__global__ __launch_bounds__(256) void k_agg(const bf16* __restrict__ G,
                                             const bf16* __restrict__ S,
                                             const float* __restrict__ es,
                                             const float* __restrict__ ed,
                                             const int* __restrict__ rp,
                                             const int* __restrict__ ss,
                                             const bf16* __restrict__ bgat,
                                             const bf16* __restrict__ bskip,
                                             void* __restrict__ out, int sout,
                                             const int* __restrict__ flags)
{
    constexpr int D  = H * C;
    constexpr int NV = (D + 3) / 4;
    constexpr int CH = 256;
    __shared__ float smx[H], sinv[H], sed[H];
    __shared__ float sal[CH * H];
    __shared__ int   ssrc[CH];

    const int n   = blockIdx.x;
    const int tid = threadIdx.x;
    int r0 = clampi(rp[n], 0, E2);
    int r1 = clampi(rp[n + 1], r0, E2);
    const int deg = r1 - r0;

    const int sw = tid >> 5, ln = tid & 31;
    for (int h = sw; h < H; h += 8) {
        float edn = ed[n * H + h];
        float mx = -1e30f;
        for (int e = ln; e < deg; e += 32) {
            int s = clampi(ss[r0 + e], 0, N_NODES - 1);
            float w = es[s * H + h] + edn;
            w = (w > 0.f) ? w : 0.2f * w;
            mx = fmaxf(mx, w);
        }
#pragma unroll
        for (int off = 16; off; off >>= 1) mx = fmaxf(mx, __shfl_xor(mx, off, 32));
        float sm = 0.f;
        for (int e = ln; e < deg; e += 32) {
            int s = clampi(ss[r0 + e], 0, N_NODES - 1);
            float w = es[s * H + h] + edn;
            w = (w > 0.f) ? w : 0.2f * w;
            sm += __expf(w - mx);
        }
#pragma unroll
        for (int off = 16; off; off >>= 1) sm += __shfl_xor(sm, off, 32);
        if (ln == 0) { smx[h] = mx; sinv[h] = 1.f / fmaxf(sm, 1e-16f); sed[h] = edn; }
    }
    __syncthreads();

    const int c0 = tid * 4;
    const int hA = (c0 < D) ? (c0 / C) : 0;            // head of channel c0
    const int hB = (c0 + 3 < D) ? ((c0 + 3) / C) : hA; // head of channel c0+3
    int hj1 = ((c0 + 1 < D) ? ((c0 + 1) / C) : hA) == hA;
    int hj2 = ((c0 + 2 < D) ? ((c0 + 2) / C) : hA) == hA;
    const bool active = (tid < NV);

    float acc[4] = {0.f, 0.f, 0.f, 0.f};

    for (int e0 = 0; e0 < deg; e0 += CH) {
        int ce = min(CH, deg - e0);
        int ce4 = (ce + 3) & ~3;
        __syncthreads();
        for (int t = tid; t < ce4 * H; t += 256) {
            int e = t / H, h = t - e * H;
            int valid = (e < ce);
            int s = valid ? clampi(ss[r0 + e0 + e], 0, N_NODES - 1) : 0;
            float w = es[s * H + h] + sed[h];
            w = (w > 0.f) ? w : 0.2f * w;
            sal[e * H + h] = valid ? __expf(w - smx[h]) * sinv[h] : 0.f;
            if (h == 0) ssrc[e] = s;
        }
        __syncthreads();
        if (active) {
            for (int eb = 0; eb < ce4; eb += 4) {
                int sg[4];
#pragma unroll
                for (int p = 0; p < 4; ++p) sg[p] = ssrc[eb + p];
                bf16x4 g[4];
#pragma unroll
                for (int p = 0; p < 4; ++p)
                    g[p] = *(const bf16x4*)(G + (size_t)sg[p] * SG + c0);
                if constexpr (C % 4 == 0) {
                    float a[4];
#pragma unroll
                    for (int p = 0; p < 4; ++p) a[p] = sal[(eb + p) * H + hA];
#pragma unroll
                    for (int p = 0; p < 4; ++p)
#pragma unroll
                        for (int j = 0; j < 4; ++j)
                            acc[j] += a[p] * (float)g[p][j];
                } else {
#pragma unroll
                    for (int p = 0; p < 4; ++p) {
                        float aL = sal[(eb + p) * H + hA];
                        float aH = sal[(eb + p) * H + hB];
                        acc[0] += aL * (float)g[p][0];
                        acc[1] += (hj1 ? aL : aH) * (float)g[p][1];
                        acc[2] += (hj2 ? aL : aH) * (float)g[p][2];
                        acc[3] += aH * (float)g[p][3];
                    }
                }
            }
        }
    }

    const int outbf = EXTOUT ? flags[1] : 1;

    if constexpr (!MEAN) {
        if (active) {
            bf16x4 bg = *(const bf16x4*)(bgat + c0);
            bf16x4 sk = *(const bf16x4*)(S + (size_t)n * SG + c0);
            bf16x4 bs = *(const bf16x4*)(bskip + c0);
            bf16x4 ov;
#pragma unroll
            for (int j = 0; j < 4; ++j) {
                float v = acc[j] + (float)bg[j] + (float)sk[j] + (float)bs[j];
                if (ELU) v = (v > 0.f) ? v : (__expf(v) - 1.f);
                ov[j] = (bf16)v;
            }
            *(bf16x4*)((bf16*)out + (size_t)n * sout + c0) = ov;
        }
    } else {
        __shared__ float sagg[D];
        if (active) {
#pragma unroll
            for (int j = 0; j < 4; ++j) {
                int c = c0 + j;
                if (c < D) sagg[c] = acc[j];
            }
        }
        __syncthreads();
        for (int c = tid; c < C; c += 256) {
            float v = 0.f;
#pragma unroll
            for (int h = 0; h < H; ++h) v += sagg[h * C + c];
            v *= (1.f / H);
            v += (float)bgat[c] + (float)S[(size_t)n * SG + c] + (float)bskip[c];
            if (outbf) ((bf16*)out)[(size_t)n * sout + c] = (bf16)v;
            else       ((float*)out)[(size_t)n * sout + c] = v;
        }
    }
}

// ----------------------------------------------------------------- launch ---
extern "C" void kernel_launch(void* const* d_in, const int* in_sizes, int n_in,
                              void* d_out, int out_size, void* d_ws, size_t ws_size,
                              hipStream_t stream)
{
    const void* x   = d_in[0];
    const int*  ei  = (const int*)d_in[1];
    const void* W1  = d_in[2];
    const void* Wl1 = d_in[6];
    const void* W2  = d_in[8];
    const void* Wl2 = d_in[12];
    const void* W3  = d_in[14];
    const void* Wl3 = d_in[18];

    P12 ps;
    ps.s[0] = d_in[3];  ps.s[1] = d_in[4];  ps.s[2] = d_in[5];  ps.s[3] = d_in[7];
    ps.s[4] = d_in[9];  ps.s[5] = d_in[10]; ps.s[6] = d_in[11]; ps.s[7] = d_in[13];
    ps.s[8] = d_in[15]; ps.s[9] = d_in[16]; ps.s[10] = d_in[17]; ps.s[11] = d_in[19];

    char* w = (char*)d_ws;
    auto alloc = [&](size_t bytes) {
        char* p = w;
        w += (bytes + 255) & ~(size_t)255;
        return p;
    };
    int*   flags = (int*)alloc(64);
    int*   cnt   = (int*)alloc((size_t)N_NODES * 4);
    int*   rp    = (int*)alloc((size_t)(N_NODES + 1) * 4);
    int*   cur   = (int*)alloc((size_t)N_NODES * 4);
    int*   ss    = (int*)alloc((size_t)E2 * 4);
    float* es    = (float*)alloc((size_t)N_NODES * 6 * 4);
    float* ed    = (float*)alloc((size_t)N_NODES * 6 * 4);
    bf16*  pool  = (bf16*)alloc((size_t)PO_END * 2);
    float* ws1   = (float*)alloc((size_t)64 * 4 * 4);
    float* wd1   = (float*)alloc((size_t)64 * 4 * 4);
    bf16*  bsum  = (bf16*)alloc((size_t)D1 * 2);
    bf16*  Bt    = (bf16*)alloc((size_t)NP12 * 1024 * 2);
    bf16*  X     = (bf16*)alloc((size_t)N_NODES * D1 * 2);   // x1/x2
    bf16*  WS    = (bf16*)alloc((size_t)N_NODES * SG * 2);   // GEMM out [gat|skip]
    bf16*  A2    = WS;   // layer-1 A'' [N x KA] aliases WS (dead during layer 1)

    k_detect<<<1, 64, 0, stream>>>(ei, (const unsigned short*)x, flags);

    hipMemsetAsync(cnt, 0, N_NODES * 4, stream);
    k_count<<<(E2 + 255) / 256, 256, 0, stream>>>(ei, cnt, flags);
    k_scan<<<1, 256, 0, stream>>>(cnt, rp, cur);
    k_fill<<<(E2 + 255) / 256, 256, 0, stream>>>(ei, cur, ss, flags);

    const dim3 blk(256);
    const int MT  = (N_NODES + 127) / 128;   // 157
    const int MT2 = (N_NODES + 255) / 256;   // 79

    // ---- layer 1: veca -> merged prep -> aggx -> GEMM (128^2, K=320)
    k_veca<<<64, 256, 0, stream>>>(W1, ps.s[0], ps.s[1], ps.s[2], ps.s[3],
                                   ws1, wd1, bsum, flags);
    k_prep<<<PB_PADX + PB_WF1 + PB_PAR + PB_LOG1, 256, 0, stream>>>(
        x, W1, Wl1, ps, A2, Bt, pool, ws1, wd1, es, ed, flags);
    k_aggx<<<N_NODES, 256, 0, stream>>>(A2, es, ed, rp, ss);
    k_gemm<true><<<MT * (D1 / 128), blk, 0, stream>>>(A2, Bt, X, N_NODES, KA, KA, KA, D1,
                                                      MT, D1 / 128, bsum);   // x1 = ELU(...)

    // ---- layer 2: K=1024, out 2048 = [GAT 1024 | skip 1024] (256^2 8-phase v2)
    k_wcatT<<<dim3(16, NP12 / 64), blk, 0, stream>>>(W2, Wl2, Bt, 1024, 1024, 1024, flags);
    k_gemm256<<<MT2 * (NP12 / 256), 512, 0, stream>>>(X, Bt, WS, N_NODES, 1024, 1024, 1024, SG,
                                                      MT2, NP12 / 256);
    k_logits<4, 256><<<N_NODES / 4, 256, 0, stream>>>(WS, pool + PO_A2S, pool + PO_A2D, es, ed);
    k_agg<4, 256, false, true, false><<<N_NODES, 256, 0, stream>>>(
        WS, WS + D1, es, ed, rp, ss, pool + PO_B2, pool + PO_BL2, X, D1, flags);

    // ---- layer 3: K=1024, out 1024 = [GAT 726 | skip 121 | pad] (256^2 8-phase v2)
    k_wcatT<<<dim3(16, NP3 / 64), blk, 0, stream>>>(W3, Wl3, Bt, 726, 726, 121, flags);
    k_gemm256<<<MT2 * (NP3 / 256), 512, 0, stream>>>(X, Bt, WS, N_NODES, 1024, 1024, 1024, SG,
                                                     MT2, NP3 / 256);
    k_logits<6, 121><<<N_NODES / 4, 256, 0, stream>>>(WS, pool + PO_A3S, pool + PO_A3D, es, ed);
    k_agg<6, 121, true, false, true><<<N_NODES, 256, 0, stream>>>(
        WS, WS + 726, es, ed, rp, ss, pool + PO_B3, pool + PO_BL3, d_out, 121, flags);
}

// Round 8
// 648.424 us; speedup vs baseline: 1.0732x; 1.0732x over previous
//
#include <hip/hip_runtime.h>
#include <hip/hip_bf16.h>
#include <math.h>

typedef __bf16 bf16;
typedef __attribute__((ext_vector_type(4))) __bf16 bf16x4;
typedef __attribute__((ext_vector_type(8))) __bf16 bf16x8;
typedef __attribute__((ext_vector_type(4))) float f32x4;

#define N_NODES 20000
#define N_EDGES 320000
#define E2 (N_EDGES + N_NODES)   // 340000 edges incl self-loops
#define F_IN 50
#define D1 1024                  // H1*C1
#define NP12 2048                // padded GEMM out-cols, layer 2 ([W|Wl])
#define NP3 896                  // padded GEMM out-cols, layer 3 (726+121=847 -> 896)
#define SG 2048                  // row stride of GEMM output buffer
#define KA 320                   // layer-1 fused K: 4*64 aggx + 64 x

// params pool element offsets (bf16 pool)
#define PO_A1S 0
#define PO_A1D 1024
#define PO_B1  2048
#define PO_BL1 3072
#define PO_A2S 4096
#define PO_A2D 5120
#define PO_B2  6144
#define PO_BL2 7168
#define PO_A3S 8192
#define PO_A3D 8918
#define PO_B3  9644
#define PO_BL3 9765
#define PO_END 9886

// k_prep block-range sizes
#define PB_PADX  5000            // N_NODES*64/256
#define PB_WF1   1280            // D1*KA/256
#define PB_PAR   39              // ceil(PO_END/256)
#define PB_LOG1  5000            // N_NODES/4

__device__ __forceinline__ int clampi(int v, int lo, int hi)
{
    return v < lo ? lo : (v > hi ? hi : v);
}

__device__ __forceinline__ float loadf(const void* p, long idx, int isb)
{
    return isb ? (float)((const bf16*)p)[idx] : ((const float*)p)[idx];
}

__device__ __forceinline__ int loadei(const int* ei, long idx, int i64)
{
    return i64 ? ei[2 * idx] : ei[idx];
}

// --------------------------------------------------------------- detect -----
__global__ void k_detect(const int* __restrict__ ei,
                         const unsigned short* __restrict__ xw,
                         int* __restrict__ flags)
{
    if (blockIdx.x != 0 || threadIdx.x != 0) return;
    int allz = 1;
    for (int i = 0; i < 128; ++i)
        if (ei[2 * i + 1] != 0) { allz = 0; break; }
    int inr = 0;
    for (int i = 0; i < 128; ++i) {
        int e = (xw[2 * i] >> 7) & 0xFF;
        if (e >= 100 && e <= 140) inr++;
    }
    flags[0] = allz;
    flags[1] = (inr >= 64) ? 1 : 0;
}

// ---------------------------------------------------------------- GEMM ------
// m97-style 128x128 tile, BK=64. BACT: fused bias+ELU epilogue.
// (256^2 8-phase line abandoned after R5/R7: 1 block/CU kills inter-block
// overlap; measured 150 then 121 us vs this kernel's 106 us at K=1024.)
template <bool BACT>
__global__ __launch_bounds__(256) void k_gemm(const bf16* __restrict__ A,
                                              const bf16* __restrict__ Bt,
                                              bf16* __restrict__ C,
                                              int M, int K, int lda, int ldb, int ldc,
                                              int mtiles, int ntiles,
                                              const bf16* __restrict__ bias)
{
    __shared__ bf16 As[128 * 64];
    __shared__ bf16 Bs[128 * 64];

    int id = blockIdx.x;
    int gfull = mtiles >> 3;
    int base  = gfull * 8 * ntiles;
    int x, y;
    if (id < base) {
        int gsz = 8 * ntiles;
        int g = id / gsz;
        int r = id - g * gsz;
        x = g * 8 + (r & 7);
        y = r >> 3;
    } else {
        int rem = mtiles - (gfull << 3);
        int r = id - base;
        x = (gfull << 3) + r % rem;
        y = r / rem;
    }
    const int m0 = x * 128;
    const int n0 = y * 128;

    const int tid  = threadIdx.x;
    const int wave = tid >> 6;
    const int lane = tid & 63;
    const int wm   = (wave >> 1) * 64;
    const int wn   = (wave & 1) * 64;
    const int frow  = lane & 15;

    const int srow = wave * 32 + (lane >> 3);
    const int scol = (((lane & 7) ^ (lane >> 3)) * 8);

    f32x4 acc[4][4];
#pragma unroll
    for (int i = 0; i < 4; ++i)
#pragma unroll
        for (int j = 0; j < 4; ++j)
#pragma unroll
            for (int r = 0; r < 4; ++r) acc[i][j][r] = 0.f;

    for (int k0 = 0; k0 < K; k0 += 64) {
#pragma unroll
        for (int i = 0; i < 4; ++i) {
            int ra = srow + i * 8;
            int ga = m0 + ra; if (ga > M - 1) ga = M - 1;   // junk rows -> discarded C rows
            __builtin_amdgcn_global_load_lds(
                (const __attribute__((address_space(1))) void*)(A + (size_t)ga * lda + k0 + scol),
                (__attribute__((address_space(3))) void*)(As + wave * 2048 + i * 512),
                16, 0, 0);
            int gb = n0 + ra;
            __builtin_amdgcn_global_load_lds(
                (const __attribute__((address_space(1))) void*)(Bt + (size_t)gb * ldb + k0 + scol),
                (__attribute__((address_space(3))) void*)(Bs + wave * 2048 + i * 512),
                16, 0, 0);
        }
        __syncthreads();
#pragma unroll
        for (int kk = 0; kk < 2; ++kk) {
            const int coff = (((kk * 4 + (lane >> 4)) ^ (frow & 7)) << 3);
            bf16x8 af[4], bfr[4];
#pragma unroll
            for (int i = 0; i < 4; ++i) {
                af[i]  = *(const bf16x8*)(As + (wm + i * 16 + frow) * 64 + coff);
                bfr[i] = *(const bf16x8*)(Bs + (wn + i * 16 + frow) * 64 + coff);
            }
#pragma unroll
            for (int i = 0; i < 4; ++i)
#pragma unroll
                for (int j = 0; j < 4; ++j)
                    acc[i][j] = __builtin_amdgcn_mfma_f32_16x16x32_bf16(af[i], bfr[j], acc[i][j], 0, 0, 0);
        }
        __syncthreads();
    }

#pragma unroll
    for (int i = 0; i < 4; ++i) {
#pragma unroll
        for (int j = 0; j < 4; ++j) {
            int rbase = m0 + wm + i * 16 + (lane >> 4) * 4;
            int col   = n0 + wn + j * 16 + frow;
            if constexpr (BACT) {
                float bv = (float)bias[col];
#pragma unroll
                for (int r = 0; r < 4; ++r) {
                    int row = rbase + r;
                    if (row < M) {
                        float v = acc[i][j][r] + bv;
                        v = (v > 0.f) ? v : (__expf(v) - 1.f);
                        C[(size_t)row * ldc + col] = (bf16)v;
                    }
                }
            } else {
#pragma unroll
                for (int r = 0; r < 4; ++r) {
                    int row = rbase + r;
                    if (row < M) C[(size_t)row * ldc + col] = (bf16)acc[i][j][r];
                }
            }
        }
    }
}

// ------------------------------------------------------------ prep kernels --
// ws[k][h] = sum_c W1[k, h*256+c]*a1s[h,c]; wd likewise; bsum = b1+bl1.
__global__ __launch_bounds__(256) void k_veca(const void* __restrict__ W1,
                                              const void* __restrict__ a1s,
                                              const void* __restrict__ a1d,
                                              const void* __restrict__ b1,
                                              const void* __restrict__ bl1,
                                              float* __restrict__ ws, float* __restrict__ wd,
                                              bf16* __restrict__ bsum,
                                              const int* __restrict__ flags)
{
    const int isb = flags[1];
    const int k = blockIdx.x;          // 0..63
    const int h = threadIdx.x >> 6;
    const int c0 = threadIdx.x & 63;
    float s = 0.f, d = 0.f;
    if (k < F_IN) {
        for (int c = c0; c < 256; c += 64) {
            float wv = loadf(W1, (long)k * D1 + h * 256 + c, isb);
            s += wv * loadf(a1s, h * 256 + c, isb);
            d += wv * loadf(a1d, h * 256 + c, isb);
        }
    }
#pragma unroll
    for (int off = 32; off; off >>= 1) {
        s += __shfl_xor(s, off);
        d += __shfl_xor(d, off);
    }
    if (c0 == 0) { ws[k * 4 + h] = s; wd[k * 4 + h] = d; }
    if (k < 4) {
        int j = k * 256 + threadIdx.x;
        bsum[j] = (bf16)(loadf(b1, j, isb) + loadf(bl1, j, isb));
    }
}

struct P12 { const void* s[12]; };

// merged prep: padx | wfuse1 | params | logits1-from-x, block-range dispatch.
__global__ __launch_bounds__(256) void k_prep(const void* __restrict__ x,
                                              const void* __restrict__ W1,
                                              const void* __restrict__ Wl1,
                                              P12 ps,
                                              bf16* __restrict__ A2,
                                              bf16* __restrict__ Bt,
                                              bf16* __restrict__ pool,
                                              const float* __restrict__ ws,
                                              const float* __restrict__ wd,
                                              float* __restrict__ es,
                                              float* __restrict__ ed,
                                              const int* __restrict__ flags)
{
    const int isb = flags[1];
    int b = blockIdx.x;

    if (b < PB_PADX) {                       // ---- x -> A2[n*KA + 256 + k]
        int idx = b * 256 + threadIdx.x;
        int n = idx >> 6, k = idx & 63;
        A2[(size_t)n * KA + 256 + k] = (k < F_IN) ? (bf16)loadf(x, (long)n * F_IN + k, isb)
                                                  : (bf16)0.f;
        return;
    }
    b -= PB_PADX;

    if (b < PB_WF1) {                        // ---- fused layer-1 B^T
        int idx = b * 256 + threadIdx.x;
        int j = idx / KA;
        int kp = idx - j * KA;
        float v = 0.f;
        if (kp < 256) {
            int hp = kp >> 6, k = kp & 63;
            if ((j >> 8) == hp && k < F_IN) v = loadf(W1, (long)k * D1 + j, isb);
        } else {
            int k = kp - 256;
            if (k < F_IN) v = loadf(Wl1, (long)k * D1 + j, isb);
        }
        Bt[idx] = (bf16)v;
        return;
    }
    b -= PB_WF1;

    if (b < PB_PAR) {                        // ---- params pool
        const int off[13] = {PO_A1S, PO_A1D, PO_B1, PO_BL1, PO_A2S, PO_A2D, PO_B2,
                             PO_BL2, PO_A3S, PO_A3D, PO_B3, PO_BL3, PO_END};
        int idx = b * 256 + threadIdx.x;
        if (idx < PO_END) {
            int seg = 0;
            while (idx >= off[seg + 1]) seg++;
            pool[idx] = (bf16)loadf(ps.s[seg], idx - off[seg], isb);
        }
        return;
    }
    b -= PB_PAR;

    // ---- layer-1 logits from x (wave per node)
    const int wave = threadIdx.x >> 6;
    const int lane = threadIdx.x & 63;
    const int n = b * 4 + wave;
    if (n >= N_NODES) return;
    float xv = (lane < F_IN) ? loadf(x, (long)n * F_IN + lane, isb) : 0.f;
    f32x4 wsv = *(const f32x4*)(ws + lane * 4);
    f32x4 wdv = *(const f32x4*)(wd + lane * 4);
    float s[4], d[4];
#pragma unroll
    for (int h = 0; h < 4; ++h) { s[h] = xv * wsv[h]; d[h] = xv * wdv[h]; }
#pragma unroll
    for (int off = 32; off; off >>= 1)
#pragma unroll
        for (int h = 0; h < 4; ++h) {
            s[h] += __shfl_xor(s[h], off);
            d[h] += __shfl_xor(d[h], off);
        }
    if (lane == 0) {
#pragma unroll
        for (int h = 0; h < 4; ++h) { es[n * 4 + h] = s[h]; ed[n * 4 + h] = d[h]; }
    }
}

// Tiled transpose-concat: Bt[n][k] = [Wa | Wb | 0](k, n), K=1024 rows.
__global__ __launch_bounds__(256) void k_wcatT(const void* __restrict__ Wa,
                                               const void* __restrict__ Wb,
                                               bf16* __restrict__ Bt,
                                               int split, int da, int db,
                                               const int* __restrict__ flags)
{
    __shared__ bf16 T[64][65];
    const int isb = flags[1];
    const int k0 = blockIdx.x * 64;
    const int n0 = blockIdx.y * 64;
    const int r = threadIdx.x >> 6;    // 0..3
    const int c = threadIdx.x & 63;
    const int n = n0 + c;
#pragma unroll
    for (int kk = 0; kk < 16; ++kk) {
        int k = k0 + r + kk * 4;
        float v = 0.f;
        if (n < split)           v = loadf(Wa, (long)k * da + n, isb);
        else if (n < split + db) v = loadf(Wb, (long)k * db + (n - split), isb);
        T[r + kk * 4][c] = (bf16)v;
    }
    __syncthreads();
#pragma unroll
    for (int kk = 0; kk < 16; ++kk) {
        int nn = r + kk * 4;
        Bt[(size_t)(n0 + nn) * 1024 + k0 + c] = T[c][nn];
    }
}

// ------------------------------------------------------------- CSR build ----
__global__ void k_count(const int* __restrict__ ei, int* __restrict__ cnt,
                        const int* __restrict__ flags)
{
    int e = blockIdx.x * 256 + threadIdx.x;
    if (e >= E2) return;
    int i64 = flags[0];
    int d = (e < N_EDGES) ? loadei(ei, (long)N_EDGES + e, i64) : (e - N_EDGES);
    d = clampi(d, 0, N_NODES - 1);
    atomicAdd(&cnt[d], 1);
}

__global__ __launch_bounds__(256) void k_scan(const int* __restrict__ cnt,
                                              int* __restrict__ rp,
                                              int* __restrict__ cur)
{
    __shared__ int ssum[256];
    int tid = threadIdx.x;
    const int chunk = (N_NODES + 255) / 256;
    int lo = tid * chunk;
    int hi = lo + chunk; if (hi > N_NODES) hi = N_NODES;
    int s = 0;
    for (int i = lo; i < hi; ++i) s += cnt[i];
    ssum[tid] = s;
    __syncthreads();
    if (tid == 0) {
        int run = 0;
        for (int i = 0; i < 256; ++i) { int t = ssum[i]; ssum[i] = run; run += t; }
        rp[N_NODES] = run;
    }
    __syncthreads();
    int run = ssum[tid];
    for (int i = lo; i < hi; ++i) { rp[i] = run; cur[i] = run; run += cnt[i]; }
}

__global__ void k_fill(const int* __restrict__ ei, int* __restrict__ cur,
                       int* __restrict__ ss, const int* __restrict__ flags)
{
    int e = blockIdx.x * 256 + threadIdx.x;
    if (e >= E2) return;
    int i64 = flags[0];
    int s, d;
    if (e < N_EDGES) {
        s = loadei(ei, e, i64);
        d = loadei(ei, (long)N_EDGES + e, i64);
    } else {
        s = e - N_EDGES; d = s;
    }
    s = clampi(s, 0, N_NODES - 1);
    d = clampi(d, 0, N_NODES - 1);
    int pos = atomicAdd(&cur[d], 1);
    if (pos >= 0 && pos < E2) ss[pos] = s;
}

// ----------------------------------------------------- attention kernels ----
// layer-1 aggregate: aggx[n,h,k] = sum_e alpha[e,h] x[src_e,k] (block per node)
__global__ __launch_bounds__(256) void k_aggx(bf16* __restrict__ A2,
                                              const float* __restrict__ es,
                                              const float* __restrict__ ed,
                                              const int* __restrict__ rp,
                                              const int* __restrict__ ss)
{
    __shared__ float smx[4], sinv[4], sed[4];
    __shared__ float sal[64 * 4];
    __shared__ int   ssrc[64];

    const int n   = blockIdx.x;
    const int tid = threadIdx.x;
    int r0 = clampi(rp[n], 0, E2);
    int r1 = clampi(rp[n + 1], r0, E2);
    const int deg = r1 - r0;

    const int sw = tid >> 5, ln = tid & 31;
    if (sw < 4) {
        int h = sw;
        float edn = ed[n * 4 + h];
        float mx = -1e30f;
        for (int e = ln; e < deg; e += 32) {
            int s = clampi(ss[r0 + e], 0, N_NODES - 1);
            float w = es[s * 4 + h] + edn;
            w = (w > 0.f) ? w : 0.2f * w;
            mx = fmaxf(mx, w);
        }
#pragma unroll
        for (int off = 16; off; off >>= 1) mx = fmaxf(mx, __shfl_xor(mx, off, 32));
        float sm = 0.f;
        for (int e = ln; e < deg; e += 32) {
            int s = clampi(ss[r0 + e], 0, N_NODES - 1);
            float w = es[s * 4 + h] + edn;
            w = (w > 0.f) ? w : 0.2f * w;
            sm += __expf(w - mx);
        }
#pragma unroll
        for (int off = 16; off; off >>= 1) sm += __shfl_xor(sm, off, 32);
        if (ln == 0) { smx[h] = mx; sinv[h] = 1.f / fmaxf(sm, 1e-16f); sed[h] = edn; }
    }
    __syncthreads();

    const int k  = tid & 63;
    const int hh = tid >> 6;
    float acc = 0.f;

    for (int e0 = 0; e0 < deg; e0 += 64) {
        int ce = min(64, deg - e0);
        int ce4 = (ce + 3) & ~3;
        __syncthreads();
        if (tid < ce4 * 4) {
            int e = tid >> 2, h = tid & 3;
            int valid = (e < ce);
            int s = valid ? clampi(ss[r0 + e0 + e], 0, N_NODES - 1) : 0;
            float w = es[s * 4 + h] + sed[h];
            w = (w > 0.f) ? w : 0.2f * w;
            sal[e * 4 + h] = valid ? __expf(w - smx[h]) * sinv[h] : 0.f;
            if (h == 0) ssrc[e] = s;
        }
        __syncthreads();
        for (int e = 0; e < ce4; e += 4) {
            float xv[4], al[4];
#pragma unroll
            for (int p = 0; p < 4; ++p) {
                int s = ssrc[e + p];
                xv[p] = (float)A2[(size_t)s * KA + 256 + k];
            }
#pragma unroll
            for (int p = 0; p < 4; ++p) al[p] = sal[(e + p) * 4 + hh];
#pragma unroll
            for (int p = 0; p < 4; ++p) acc += al[p] * xv[p];
        }
    }
    A2[(size_t)n * KA + hh * 64 + k] = (bf16)acc;
}

// layers 2/3 logits on h (wave per node)
template <int H, int C>
__global__ __launch_bounds__(256) void k_logits(const bf16* __restrict__ G,
                                                const bf16* __restrict__ as_,
                                                const bf16* __restrict__ ad_,
                                                float* __restrict__ es, float* __restrict__ ed)
{
    const int wave = threadIdx.x >> 6;
    const int lane = threadIdx.x & 63;
    const int n = blockIdx.x * 4 + wave;
    if (n >= N_NODES) return;

#pragma unroll
    for (int h = 0; h < H; ++h) {
        float s = 0.f, d = 0.f;
        if constexpr (C == 256) {
            bf16x4 g  = *(const bf16x4*)(G + (size_t)n * SG + h * 256 + lane * 4);
            bf16x4 av = *(const bf16x4*)(as_ + h * 256 + lane * 4);
            bf16x4 dv = *(const bf16x4*)(ad_ + h * 256 + lane * 4);
#pragma unroll
            for (int j = 0; j < 4; ++j) {
                float gv = (float)g[j];
                s += gv * (float)av[j];
                d += gv * (float)dv[j];
            }
        } else {
            for (int c = lane; c < C; c += 64) {
                float hv = (float)G[(size_t)n * SG + h * C + c];
                s += hv * (float)as_[h * C + c];
                d += hv * (float)ad_[h * C + c];
            }
        }
#pragma unroll
        for (int off = 32; off; off >>= 1) {
            s += __shfl_xor(s, off);
            d += __shfl_xor(d, off);
        }
        if (lane == 0) { es[n * H + h] = s; ed[n * H + h] = d; }
    }
}

// R7: wave-per-node aggregate for layer 2 (H=4, C=256, D=1024).
// One wave per node, 4 independent waves/block, ZERO barriers.
// Lane owns 16 channels (head = lane>>4, exact since 16|256).
// Pass A: online-softmax stats, all 64 lanes over edges (es is L2-resident).
// Pass B per 64-edge chunk: alpha fill (1 edge/lane, stride-1 LDS writes)
// then guard-free 4-edge-batch gather with 2x bf16x8 (32B/lane/edge).
__global__ __launch_bounds__(256) void k_aggw(const bf16* __restrict__ G,
                                              const bf16* __restrict__ S,
                                              const float* __restrict__ es,
                                              const float* __restrict__ ed,
                                              const int* __restrict__ rp,
                                              const int* __restrict__ ss,
                                              const bf16* __restrict__ bgat,
                                              const bf16* __restrict__ bskip,
                                              bf16* __restrict__ out, int sout)
{
    __shared__ float sal[4][4][65];    // [wave][head][edge] (+pad: conflict-free 4-head read)
    __shared__ int   ssrc[4][64];

    const int w    = threadIdx.x >> 6;
    const int lane = threadIdx.x & 63;
    const int n    = blockIdx.x * 4 + w;
    if (n >= N_NODES) return;

    int r0 = clampi(rp[n], 0, E2);
    int r1 = clampi(rp[n + 1], r0, E2);
    const int deg = r1 - r0;

    f32x4 edn = *(const f32x4*)(ed + n * 4);

    // ---- pass A: online max+sum (replicated across lanes via all-reduce)
    float mx[4] = {-1e30f, -1e30f, -1e30f, -1e30f};
    float sm[4] = {0.f, 0.f, 0.f, 0.f};
    for (int c0 = 0; c0 < deg; c0 += 64) {
        const int e = c0 + lane;
        const bool val = (e < deg);
        const int s = val ? clampi(ss[r0 + e], 0, N_NODES - 1) : 0;
        f32x4 esv = *(const f32x4*)(es + s * 4);
        float w4[4], mc[4];
#pragma unroll
        for (int h = 0; h < 4; ++h) {
            float v = esv[h] + edn[h];
            v = (v > 0.f) ? v : 0.2f * v;
            w4[h] = val ? v : -1e30f;
            mc[h] = w4[h];
        }
#pragma unroll
        for (int off = 32; off; off >>= 1)
#pragma unroll
            for (int h = 0; h < 4; ++h) mc[h] = fmaxf(mc[h], __shfl_xor(mc[h], off));
        float ps[4];
#pragma unroll
        for (int h = 0; h < 4; ++h) {
            float mn = fmaxf(mx[h], mc[h]);
            float f  = __expf(mx[h] - mn);      // first chunk: exp(-huge)=0
            ps[h] = __expf(w4[h] - mn);         // invalid lanes: exp(-huge)=0
            mx[h] = mn;
            sm[h] *= f;
        }
#pragma unroll
        for (int off = 32; off; off >>= 1)
#pragma unroll
            for (int h = 0; h < 4; ++h) ps[h] += __shfl_xor(ps[h], off);
#pragma unroll
        for (int h = 0; h < 4; ++h) sm[h] += ps[h];
    }
    float sinv[4];
#pragma unroll
    for (int h = 0; h < 4; ++h) sinv[h] = 1.f / fmaxf(sm[h], 1e-16f);

    // ---- pass B: per-chunk alpha fill + gather
    const int myh  = lane >> 4;        // head of this lane's channels
    const int c0ch = lane * 16;        // channel base (16 ch/lane)
    float acc[16];
#pragma unroll
    for (int j = 0; j < 16; ++j) acc[j] = 0.f;

    for (int c0 = 0; c0 < deg; c0 += 64) {
        const int ce = min(64, deg - c0);
        const bool val = (lane < ce);
        const int e = c0 + lane;
        const int s = val ? clampi(ss[r0 + e], 0, N_NODES - 1) : 0;
        f32x4 esv = *(const f32x4*)(es + s * 4);
#pragma unroll
        for (int h = 0; h < 4; ++h) {
            float v = esv[h] + edn[h];
            v = (v > 0.f) ? v : 0.2f * v;
            sal[w][h][lane] = val ? __expf(v - mx[h]) * sinv[h] : 0.f;
        }
        ssrc[w][lane] = s;
        // wave-synchronous: compiler inserts lgkmcnt for the LDS RAW below.
        const int ce4 = (ce + 3) & ~3;
        for (int eb = 0; eb < ce4; eb += 4) {
            int sg[4]; float a[4];
#pragma unroll
            for (int p = 0; p < 4; ++p) {
                sg[p] = ssrc[w][eb + p];
                a[p]  = sal[w][myh][eb + p];
            }
            bf16x8 g0[4], g1[4];
#pragma unroll
            for (int p = 0; p < 4; ++p) {
                const bf16* gp = G + (size_t)sg[p] * SG + c0ch;
                g0[p] = *(const bf16x8*)gp;
                g1[p] = *(const bf16x8*)(gp + 8);
            }
#pragma unroll
            for (int p = 0; p < 4; ++p) {
#pragma unroll
                for (int j = 0; j < 8; ++j) acc[j]     += a[p] * (float)g0[p][j];
#pragma unroll
                for (int j = 0; j < 8; ++j) acc[j + 8] += a[p] * (float)g1[p][j];
            }
        }
    }

    // ---- epilogue: + bgat + skip + bskip, ELU, store 32B
    bf16x8 bg0 = *(const bf16x8*)(bgat + c0ch);
    bf16x8 bg1 = *(const bf16x8*)(bgat + c0ch + 8);
    bf16x8 sk0 = *(const bf16x8*)(S + (size_t)n * SG + c0ch);
    bf16x8 sk1 = *(const bf16x8*)(S + (size_t)n * SG + c0ch + 8);
    bf16x8 bs0 = *(const bf16x8*)(bskip + c0ch);
    bf16x8 bs1 = *(const bf16x8*)(bskip + c0ch + 8);
    bf16x8 ov0, ov1;
#pragma unroll
    for (int j = 0; j < 8; ++j) {
        float v = acc[j] + (float)bg0[j] + (float)sk0[j] + (float)bs0[j];
        v = (v > 0.f) ? v : (__expf(v) - 1.f);
        ov0[j] = (bf16)v;
        float u = acc[j + 8] + (float)bg1[j] + (float)sk1[j] + (float)bs1[j];
        u = (u > 0.f) ? u : (__expf(u) - 1.f);
        ov1[j] = (bf16)u;
    }
    *(bf16x8*)(out + (size_t)n * sout + c0ch)     = ov0;
    *(bf16x8*)(out + (size_t)n * sout + c0ch + 8) = ov1;
}

// Fused per-dst-node softmax + gather-aggregate + bias + skip (+mean/ELU).
// Template version kept for layer 3 (C=121: messy head boundaries).
template <int H, int C, bool MEAN, bool ELU, bool EXTOUT>
__global__ __launch_bounds__(256) void k_agg(const bf16* __restrict__ G,
                                             const bf16* __restrict__ S,
                                             const float* __restrict__ es,
                                             const float* __restrict__ ed,
                                             const int* __restrict__ rp,
                                             const int* __restrict__ ss,
                                             const bf16* __restrict__ bgat,
                                             const bf16* __restrict__ bskip,
                                             void* __restrict__ out, int sout,
                                             const int* __restrict__ flags)
{
    constexpr int D  = H * C;
    constexpr int NV = (D + 3) / 4;
    constexpr int CH = 256;
    __shared__ float smx[H], sinv[H], sed[H];
    __shared__ float sal[CH * H];
    __shared__ int   ssrc[CH];

    const int n   = blockIdx.x;
    const int tid = threadIdx.x;
    int r0 = clampi(rp[n], 0, E2);
    int r1 = clampi(rp[n + 1], r0, E2);
    const int deg = r1 - r0;

    const int sw = tid >> 5, ln = tid & 31;
    for (int h = sw; h < H; h += 8) {
        float edn = ed[n * H + h];
        float mx = -1e30f;
        for (int e = ln; e < deg; e += 32) {
            int s = clampi(ss[r0 + e], 0, N_NODES - 1);
            float w = es[s * H + h] + edn;
            w = (w > 0.f) ? w : 0.2f * w;
            mx = fmaxf(mx, w);
        }
#pragma unroll
        for (int off = 16; off; off >>= 1) mx = fmaxf(mx, __shfl_xor(mx, off, 32));
        float sm = 0.f;
        for (int e = ln; e < deg; e += 32) {
            int s = clampi(ss[r0 + e], 0, N_NODES - 1);
            float w = es[s * H + h] + edn;
            w = (w > 0.f) ? w : 0.2f * w;
            sm += __expf(w - mx);
        }
#pragma unroll
        for (int off = 16; off; off >>= 1) sm += __shfl_xor(sm, off, 32);
        if (ln == 0) { smx[h] = mx; sinv[h] = 1.f / fmaxf(sm, 1e-16f); sed[h] = edn; }
    }
    __syncthreads();

    const int c0 = tid * 4;
    const int hA = (c0 < D) ? (c0 / C) : 0;            // head of channel c0
    const int hB = (c0 + 3 < D) ? ((c0 + 3) / C) : hA; // head of channel c0+3
    int hj1 = ((c0 + 1 < D) ? ((c0 + 1) / C) : hA) == hA;
    int hj2 = ((c0 + 2 < D) ? ((c0 + 2) / C) : hA) == hA;
    const bool active = (tid < NV);

    float acc[4] = {0.f, 0.f, 0.f, 0.f};

    for (int e0 = 0; e0 < deg; e0 += CH) {
        int ce = min(CH, deg - e0);
        int ce4 = (ce + 3) & ~3;
        __syncthreads();
        for (int t = tid; t < ce4 * H; t += 256) {
            int e = t / H, h = t - e * H;
            int valid = (e < ce);
            int s = valid ? clampi(ss[r0 + e0 + e], 0, N_NODES - 1) : 0;
            float w = es[s * H + h] + sed[h];
            w = (w > 0.f) ? w : 0.2f * w;
            sal[e * H + h] = valid ? __expf(w - smx[h]) * sinv[h] : 0.f;
            if (h == 0) ssrc[e] = s;
        }
        __syncthreads();
        if (active) {
            for (int eb = 0; eb < ce4; eb += 4) {
                int sg[4];
#pragma unroll
                for (int p = 0; p < 4; ++p) sg[p] = ssrc[eb + p];
                bf16x4 g[4];
#pragma unroll
                for (int p = 0; p < 4; ++p)
                    g[p] = *(const bf16x4*)(G + (size_t)sg[p] * SG + c0);
                if constexpr (C % 4 == 0) {
                    float a[4];
#pragma unroll
                    for (int p = 0; p < 4; ++p) a[p] = sal[(eb + p) * H + hA];
#pragma unroll
                    for (int p = 0; p < 4; ++p)
#pragma unroll
                        for (int j = 0; j < 4; ++j)
                            acc[j] += a[p] * (float)g[p][j];
                } else {
#pragma unroll
                    for (int p = 0; p < 4; ++p) {
                        float aL = sal[(eb + p) * H + hA];
                        float aH = sal[(eb + p) * H + hB];
                        acc[0] += aL * (float)g[p][0];
                        acc[1] += (hj1 ? aL : aH) * (float)g[p][1];
                        acc[2] += (hj2 ? aL : aH) * (float)g[p][2];
                        acc[3] += aH * (float)g[p][3];
                    }
                }
            }
        }
    }

    const int outbf = EXTOUT ? flags[1] : 1;

    if constexpr (!MEAN) {
        if (active) {
            bf16x4 bg = *(const bf16x4*)(bgat + c0);
            bf16x4 sk = *(const bf16x4*)(S + (size_t)n * SG + c0);
            bf16x4 bs = *(const bf16x4*)(bskip + c0);
            bf16x4 ov;
#pragma unroll
            for (int j = 0; j < 4; ++j) {
                float v = acc[j] + (float)bg[j] + (float)sk[j] + (float)bs[j];
                if (ELU) v = (v > 0.f) ? v : (__expf(v) - 1.f);
                ov[j] = (bf16)v;
            }
            *(bf16x4*)((bf16*)out + (size_t)n * sout + c0) = ov;
        }
    } else {
        __shared__ float sagg[D];
        if (active) {
#pragma unroll
            for (int j = 0; j < 4; ++j) {
                int c = c0 + j;
                if (c < D) sagg[c] = acc[j];
            }
        }
        __syncthreads();
        for (int c = tid; c < C; c += 256) {
            float v = 0.f;
#pragma unroll
            for (int h = 0; h < H; ++h) v += sagg[h * C + c];
            v *= (1.f / H);
            v += (float)bgat[c] + (float)S[(size_t)n * SG + c] + (float)bskip[c];
            if (outbf) ((bf16*)out)[(size_t)n * sout + c] = (bf16)v;
            else       ((float*)out)[(size_t)n * sout + c] = v;
        }
    }
}

// ----------------------------------------------------------------- launch ---
extern "C" void kernel_launch(void* const* d_in, const int* in_sizes, int n_in,
                              void* d_out, int out_size, void* d_ws, size_t ws_size,
                              hipStream_t stream)
{
    const void* x   = d_in[0];
    const int*  ei  = (const int*)d_in[1];
    const void* W1  = d_in[2];
    const void* Wl1 = d_in[6];
    const void* W2  = d_in[8];
    const void* Wl2 = d_in[12];
    const void* W3  = d_in[14];
    const void* Wl3 = d_in[18];

    P12 ps;
    ps.s[0] = d_in[3];  ps.s[1] = d_in[4];  ps.s[2] = d_in[5];  ps.s[3] = d_in[7];
    ps.s[4] = d_in[9];  ps.s[5] = d_in[10]; ps.s[6] = d_in[11]; ps.s[7] = d_in[13];
    ps.s[8] = d_in[15]; ps.s[9] = d_in[16]; ps.s[10] = d_in[17]; ps.s[11] = d_in[19];

    char* w = (char*)d_ws;
    auto alloc = [&](size_t bytes) {
        char* p = w;
        w += (bytes + 255) & ~(size_t)255;
        return p;
    };
    int*   flags = (int*)alloc(64);
    int*   cnt   = (int*)alloc((size_t)N_NODES * 4);
    int*   rp    = (int*)alloc((size_t)(N_NODES + 1) * 4);
    int*   cur   = (int*)alloc((size_t)N_NODES * 4);
    int*   ss    = (int*)alloc((size_t)E2 * 4);
    float* es    = (float*)alloc((size_t)N_NODES * 6 * 4);
    float* ed    = (float*)alloc((size_t)N_NODES * 6 * 4);
    bf16*  pool  = (bf16*)alloc((size_t)PO_END * 2);
    float* ws1   = (float*)alloc((size_t)64 * 4 * 4);
    float* wd1   = (float*)alloc((size_t)64 * 4 * 4);
    bf16*  bsum  = (bf16*)alloc((size_t)D1 * 2);
    bf16*  Bt    = (bf16*)alloc((size_t)NP12 * 1024 * 2);
    bf16*  X     = (bf16*)alloc((size_t)N_NODES * D1 * 2);   // x1/x2
    bf16*  WS    = (bf16*)alloc((size_t)N_NODES * SG * 2);   // GEMM out [gat|skip]
    bf16*  A2    = WS;   // layer-1 A'' [N x KA] aliases WS (dead during layer 1)

    k_detect<<<1, 64, 0, stream>>>(ei, (const unsigned short*)x, flags);

    hipMemsetAsync(cnt, 0, N_NODES * 4, stream);
    k_count<<<(E2 + 255) / 256, 256, 0, stream>>>(ei, cnt, flags);
    k_scan<<<1, 256, 0, stream>>>(cnt, rp, cur);
    k_fill<<<(E2 + 255) / 256, 256, 0, stream>>>(ei, cur, ss, flags);

    const dim3 blk(256);
    const int MT = (N_NODES + 127) / 128;   // 157

    // ---- layer 1: veca -> merged prep -> aggx -> GEMM (128^2, K=320)
    k_veca<<<64, 256, 0, stream>>>(W1, ps.s[0], ps.s[1], ps.s[2], ps.s[3],
                                   ws1, wd1, bsum, flags);
    k_prep<<<PB_PADX + PB_WF1 + PB_PAR + PB_LOG1, 256, 0, stream>>>(
        x, W1, Wl1, ps, A2, Bt, pool, ws1, wd1, es, ed, flags);
    k_aggx<<<N_NODES, 256, 0, stream>>>(A2, es, ed, rp, ss);
    k_gemm<true><<<MT * (D1 / 128), blk, 0, stream>>>(A2, Bt, X, N_NODES, KA, KA, KA, D1,
                                                      MT, D1 / 128, bsum);   // x1 = ELU(...)

    // ---- layer 2: K=1024, out 2048 = [GAT 1024 | skip 1024]
    k_wcatT<<<dim3(16, NP12 / 64), blk, 0, stream>>>(W2, Wl2, Bt, 1024, 1024, 1024, flags);
    k_gemm<false><<<MT * (NP12 / 128), blk, 0, stream>>>(X, Bt, WS, N_NODES, 1024, 1024, 1024, SG,
                                                         MT, NP12 / 128, nullptr);
    k_logits<4, 256><<<N_NODES / 4, 256, 0, stream>>>(WS, pool + PO_A2S, pool + PO_A2D, es, ed);
    k_aggw<<<N_NODES / 4, 256, 0, stream>>>(
        WS, WS + D1, es, ed, rp, ss, pool + PO_B2, pool + PO_BL2, X, D1);

    // ---- layer 3: K=1024, out 896 = [GAT 726 | skip 121 | pad]
    k_wcatT<<<dim3(16, NP3 / 64), blk, 0, stream>>>(W3, Wl3, Bt, 726, 726, 121, flags);
    k_gemm<false><<<MT * (NP3 / 128), blk, 0, stream>>>(X, Bt, WS, N_NODES, 1024, 1024, 1024, SG,
                                                        MT, NP3 / 128, nullptr);
    k_logits<6, 121><<<N_NODES / 4, 256, 0, stream>>>(WS, pool + PO_A3S, pool + PO_A3D, es, ed);
    k_agg<6, 121, true, false, true><<<N_NODES, 256, 0, stream>>>(
        WS, WS + 726, es, ed, rp, ss, pool + PO_B3, pool + PO_BL3, d_out, 121, flags);
}

// Round 9
// 635.020 us; speedup vs baseline: 1.0959x; 1.0211x over previous
//
#include <hip/hip_runtime.h>
#include <hip/hip_bf16.h>
#include <math.h>

typedef __bf16 bf16;
typedef __attribute__((ext_vector_type(4))) __bf16 bf16x4;
typedef __attribute__((ext_vector_type(8))) __bf16 bf16x8;
typedef __attribute__((ext_vector_type(4))) float f32x4;

#define N_NODES 20000
#define N_EDGES 320000
#define E2 (N_EDGES + N_NODES)   // 340000 edges incl self-loops
#define F_IN 50
#define D1 1024                  // H1*C1
#define NP12 2048                // padded GEMM out-cols, layer 2 ([W|Wl])
#define NP3 896                  // padded GEMM out-cols, layer 3 (726+121=847 -> 896)
#define SG 2048                  // row stride of GEMM output buffer
#define KA 320                   // layer-1 fused K: 4*64 aggx + 64 x

// params pool element offsets (bf16 pool)
#define PO_A1S 0
#define PO_A1D 1024
#define PO_B1  2048
#define PO_BL1 3072
#define PO_A2S 4096
#define PO_A2D 5120
#define PO_B2  6144
#define PO_BL2 7168
#define PO_A3S 8192
#define PO_A3D 8918
#define PO_B3  9644
#define PO_BL3 9765
#define PO_END 9886

// k_prep block-range sizes
#define PB_PADX  5000            // N_NODES*64/256
#define PB_WF1   1280            // D1*KA/256
#define PB_PAR   39              // ceil(PO_END/256)
#define PB_LOG1  5000            // N_NODES/4

__device__ __forceinline__ int clampi(int v, int lo, int hi)
{
    return v < lo ? lo : (v > hi ? hi : v);
}

__device__ __forceinline__ float loadf(const void* p, long idx, int isb)
{
    return isb ? (float)((const bf16*)p)[idx] : ((const float*)p)[idx];
}

__device__ __forceinline__ int loadei(const int* ei, long idx, int i64)
{
    return i64 ? ei[2 * idx] : ei[idx];
}

// --------------------------------------------------------------- detect -----
__global__ void k_detect(const int* __restrict__ ei,
                         const unsigned short* __restrict__ xw,
                         int* __restrict__ flags)
{
    if (blockIdx.x != 0 || threadIdx.x != 0) return;
    int allz = 1;
    for (int i = 0; i < 128; ++i)
        if (ei[2 * i + 1] != 0) { allz = 0; break; }
    int inr = 0;
    for (int i = 0; i < 128; ++i) {
        int e = (xw[2 * i] >> 7) & 0xFF;
        if (e >= 100 && e <= 140) inr++;
    }
    flags[0] = allz;
    flags[1] = (inr >= 64) ? 1 : 0;
}

// ---------------------------------------------------------------- GEMM ------
// m97-style 128x128 tile, BK=64. BACT: fused bias+ELU epilogue.
// (256^2 8-phase line abandoned after R5/R7: 1 block/CU kills inter-block
// overlap; measured 150 then 121 us vs this kernel's 106 us at K=1024.)
template <bool BACT>
__global__ __launch_bounds__(256) void k_gemm(const bf16* __restrict__ A,
                                              const bf16* __restrict__ Bt,
                                              bf16* __restrict__ C,
                                              int M, int K, int lda, int ldb, int ldc,
                                              int mtiles, int ntiles,
                                              const bf16* __restrict__ bias)
{
    __shared__ bf16 As[128 * 64];
    __shared__ bf16 Bs[128 * 64];

    int id = blockIdx.x;
    int gfull = mtiles >> 3;
    int base  = gfull * 8 * ntiles;
    int x, y;
    if (id < base) {
        int gsz = 8 * ntiles;
        int g = id / gsz;
        int r = id - g * gsz;
        x = g * 8 + (r & 7);
        y = r >> 3;
    } else {
        int rem = mtiles - (gfull << 3);
        int r = id - base;
        x = (gfull << 3) + r % rem;
        y = r / rem;
    }
    const int m0 = x * 128;
    const int n0 = y * 128;

    const int tid  = threadIdx.x;
    const int wave = tid >> 6;
    const int lane = tid & 63;
    const int wm   = (wave >> 1) * 64;
    const int wn   = (wave & 1) * 64;
    const int frow  = lane & 15;

    const int srow = wave * 32 + (lane >> 3);
    const int scol = (((lane & 7) ^ (lane >> 3)) * 8);

    f32x4 acc[4][4];
#pragma unroll
    for (int i = 0; i < 4; ++i)
#pragma unroll
        for (int j = 0; j < 4; ++j)
#pragma unroll
            for (int r = 0; r < 4; ++r) acc[i][j][r] = 0.f;

    for (int k0 = 0; k0 < K; k0 += 64) {
#pragma unroll
        for (int i = 0; i < 4; ++i) {
            int ra = srow + i * 8;
            int ga = m0 + ra; if (ga > M - 1) ga = M - 1;   // junk rows -> discarded C rows
            __builtin_amdgcn_global_load_lds(
                (const __attribute__((address_space(1))) void*)(A + (size_t)ga * lda + k0 + scol),
                (__attribute__((address_space(3))) void*)(As + wave * 2048 + i * 512),
                16, 0, 0);
            int gb = n0 + ra;
            __builtin_amdgcn_global_load_lds(
                (const __attribute__((address_space(1))) void*)(Bt + (size_t)gb * ldb + k0 + scol),
                (__attribute__((address_space(3))) void*)(Bs + wave * 2048 + i * 512),
                16, 0, 0);
        }
        __syncthreads();
#pragma unroll
        for (int kk = 0; kk < 2; ++kk) {
            const int coff = (((kk * 4 + (lane >> 4)) ^ (frow & 7)) << 3);
            bf16x8 af[4], bfr[4];
#pragma unroll
            for (int i = 0; i < 4; ++i) {
                af[i]  = *(const bf16x8*)(As + (wm + i * 16 + frow) * 64 + coff);
                bfr[i] = *(const bf16x8*)(Bs + (wn + i * 16 + frow) * 64 + coff);
            }
#pragma unroll
            for (int i = 0; i < 4; ++i)
#pragma unroll
                for (int j = 0; j < 4; ++j)
                    acc[i][j] = __builtin_amdgcn_mfma_f32_16x16x32_bf16(af[i], bfr[j], acc[i][j], 0, 0, 0);
        }
        __syncthreads();
    }

#pragma unroll
    for (int i = 0; i < 4; ++i) {
#pragma unroll
        for (int j = 0; j < 4; ++j) {
            int rbase = m0 + wm + i * 16 + (lane >> 4) * 4;
            int col   = n0 + wn + j * 16 + frow;
            if constexpr (BACT) {
                float bv = (float)bias[col];
#pragma unroll
                for (int r = 0; r < 4; ++r) {
                    int row = rbase + r;
                    if (row < M) {
                        float v = acc[i][j][r] + bv;
                        v = (v > 0.f) ? v : (__expf(v) - 1.f);
                        C[(size_t)row * ldc + col] = (bf16)v;
                    }
                }
            } else {
#pragma unroll
                for (int r = 0; r < 4; ++r) {
                    int row = rbase + r;
                    if (row < M) C[(size_t)row * ldc + col] = (bf16)acc[i][j][r];
                }
            }
        }
    }
}

// ------------------------------------------------------------ prep kernels --
// ws[k][h] = sum_c W1[k, h*256+c]*a1s[h,c]; wd likewise; bsum = b1+bl1.
__global__ __launch_bounds__(256) void k_veca(const void* __restrict__ W1,
                                              const void* __restrict__ a1s,
                                              const void* __restrict__ a1d,
                                              const void* __restrict__ b1,
                                              const void* __restrict__ bl1,
                                              float* __restrict__ ws, float* __restrict__ wd,
                                              bf16* __restrict__ bsum,
                                              const int* __restrict__ flags)
{
    const int isb = flags[1];
    const int k = blockIdx.x;          // 0..63
    const int h = threadIdx.x >> 6;
    const int c0 = threadIdx.x & 63;
    float s = 0.f, d = 0.f;
    if (k < F_IN) {
        for (int c = c0; c < 256; c += 64) {
            float wv = loadf(W1, (long)k * D1 + h * 256 + c, isb);
            s += wv * loadf(a1s, h * 256 + c, isb);
            d += wv * loadf(a1d, h * 256 + c, isb);
        }
    }
#pragma unroll
    for (int off = 32; off; off >>= 1) {
        s += __shfl_xor(s, off);
        d += __shfl_xor(d, off);
    }
    if (c0 == 0) { ws[k * 4 + h] = s; wd[k * 4 + h] = d; }
    if (k < 4) {
        int j = k * 256 + threadIdx.x;
        bsum[j] = (bf16)(loadf(b1, j, isb) + loadf(bl1, j, isb));
    }
}

struct P12 { const void* s[12]; };

// merged prep: padx | wfuse1 | params | logits1-from-x, block-range dispatch.
__global__ __launch_bounds__(256) void k_prep(const void* __restrict__ x,
                                              const void* __restrict__ W1,
                                              const void* __restrict__ Wl1,
                                              P12 ps,
                                              bf16* __restrict__ A2,
                                              bf16* __restrict__ Bt,
                                              bf16* __restrict__ pool,
                                              const float* __restrict__ ws,
                                              const float* __restrict__ wd,
                                              float* __restrict__ es,
                                              float* __restrict__ ed,
                                              const int* __restrict__ flags)
{
    const int isb = flags[1];
    int b = blockIdx.x;

    if (b < PB_PADX) {                       // ---- x -> A2[n*KA + 256 + k]
        int idx = b * 256 + threadIdx.x;
        int n = idx >> 6, k = idx & 63;
        A2[(size_t)n * KA + 256 + k] = (k < F_IN) ? (bf16)loadf(x, (long)n * F_IN + k, isb)
                                                  : (bf16)0.f;
        return;
    }
    b -= PB_PADX;

    if (b < PB_WF1) {                        // ---- fused layer-1 B^T
        int idx = b * 256 + threadIdx.x;
        int j = idx / KA;
        int kp = idx - j * KA;
        float v = 0.f;
        if (kp < 256) {
            int hp = kp >> 6, k = kp & 63;
            if ((j >> 8) == hp && k < F_IN) v = loadf(W1, (long)k * D1 + j, isb);
        } else {
            int k = kp - 256;
            if (k < F_IN) v = loadf(Wl1, (long)k * D1 + j, isb);
        }
        Bt[idx] = (bf16)v;
        return;
    }
    b -= PB_WF1;

    if (b < PB_PAR) {                        // ---- params pool
        const int off[13] = {PO_A1S, PO_A1D, PO_B1, PO_BL1, PO_A2S, PO_A2D, PO_B2,
                             PO_BL2, PO_A3S, PO_A3D, PO_B3, PO_BL3, PO_END};
        int idx = b * 256 + threadIdx.x;
        if (idx < PO_END) {
            int seg = 0;
            while (idx >= off[seg + 1]) seg++;
            pool[idx] = (bf16)loadf(ps.s[seg], idx - off[seg], isb);
        }
        return;
    }
    b -= PB_PAR;

    // ---- layer-1 logits from x (wave per node)
    const int wave = threadIdx.x >> 6;
    const int lane = threadIdx.x & 63;
    const int n = b * 4 + wave;
    if (n >= N_NODES) return;
    float xv = (lane < F_IN) ? loadf(x, (long)n * F_IN + lane, isb) : 0.f;
    f32x4 wsv = *(const f32x4*)(ws + lane * 4);
    f32x4 wdv = *(const f32x4*)(wd + lane * 4);
    float s[4], d[4];
#pragma unroll
    for (int h = 0; h < 4; ++h) { s[h] = xv * wsv[h]; d[h] = xv * wdv[h]; }
#pragma unroll
    for (int off = 32; off; off >>= 1)
#pragma unroll
        for (int h = 0; h < 4; ++h) {
            s[h] += __shfl_xor(s[h], off);
            d[h] += __shfl_xor(d[h], off);
        }
    if (lane == 0) {
#pragma unroll
        for (int h = 0; h < 4; ++h) { es[n * 4 + h] = s[h]; ed[n * 4 + h] = d[h]; }
    }
}

// Tiled transpose-concat: Bt[n][k] = [Wa | Wb | 0](k, n), K=1024 rows.
__global__ __launch_bounds__(256) void k_wcatT(const void* __restrict__ Wa,
                                               const void* __restrict__ Wb,
                                               bf16* __restrict__ Bt,
                                               int split, int da, int db,
                                               const int* __restrict__ flags)
{
    __shared__ bf16 T[64][65];
    const int isb = flags[1];
    const int k0 = blockIdx.x * 64;
    const int n0 = blockIdx.y * 64;
    const int r = threadIdx.x >> 6;    // 0..3
    const int c = threadIdx.x & 63;
    const int n = n0 + c;
#pragma unroll
    for (int kk = 0; kk < 16; ++kk) {
        int k = k0 + r + kk * 4;
        float v = 0.f;
        if (n < split)           v = loadf(Wa, (long)k * da + n, isb);
        else if (n < split + db) v = loadf(Wb, (long)k * db + (n - split), isb);
        T[r + kk * 4][c] = (bf16)v;
    }
    __syncthreads();
#pragma unroll
    for (int kk = 0; kk < 16; ++kk) {
        int nn = r + kk * 4;
        Bt[(size_t)(n0 + nn) * 1024 + k0 + c] = T[c][nn];
    }
}

// ------------------------------------------------------------- CSR build ----
__global__ void k_count(const int* __restrict__ ei, int* __restrict__ cnt,
                        const int* __restrict__ flags)
{
    int e = blockIdx.x * 256 + threadIdx.x;
    if (e >= E2) return;
    int i64 = flags[0];
    int d = (e < N_EDGES) ? loadei(ei, (long)N_EDGES + e, i64) : (e - N_EDGES);
    d = clampi(d, 0, N_NODES - 1);
    atomicAdd(&cnt[d], 1);
}

__global__ __launch_bounds__(256) void k_scan(const int* __restrict__ cnt,
                                              int* __restrict__ rp,
                                              int* __restrict__ cur)
{
    __shared__ int ssum[256];
    int tid = threadIdx.x;
    const int chunk = (N_NODES + 255) / 256;
    int lo = tid * chunk;
    int hi = lo + chunk; if (hi > N_NODES) hi = N_NODES;
    int s = 0;
    for (int i = lo; i < hi; ++i) s += cnt[i];
    ssum[tid] = s;
    __syncthreads();
    if (tid == 0) {
        int run = 0;
        for (int i = 0; i < 256; ++i) { int t = ssum[i]; ssum[i] = run; run += t; }
        rp[N_NODES] = run;
    }
    __syncthreads();
    int run = ssum[tid];
    for (int i = lo; i < hi; ++i) { rp[i] = run; cur[i] = run; run += cnt[i]; }
}

__global__ void k_fill(const int* __restrict__ ei, int* __restrict__ cur,
                       int* __restrict__ ss, const int* __restrict__ flags)
{
    int e = blockIdx.x * 256 + threadIdx.x;
    if (e >= E2) return;
    int i64 = flags[0];
    int s, d;
    if (e < N_EDGES) {
        s = loadei(ei, e, i64);
        d = loadei(ei, (long)N_EDGES + e, i64);
    } else {
        s = e - N_EDGES; d = s;
    }
    s = clampi(s, 0, N_NODES - 1);
    d = clampi(d, 0, N_NODES - 1);
    int pos = atomicAdd(&cur[d], 1);
    if (pos >= 0 && pos < E2) ss[pos] = s;
}

// ----------------------------------------------------- attention kernels ----
// R8: wave-per-node layer-1 aggregate. 4 nodes/block, ZERO barriers.
// Pass B gathers 8 edges per wave-instruction: lane (g=l>>3 edge-slot,
// cb=(l&7)*8 channel-block) reads x[ssrc[eb+g]][cb..cb+8) as bf16x8
// (1KB/wave/instr, fully coalesced), accumulates 4 heads x 8 ch; final
// 3-step butterfly fold (xor 8/16/32) sums across edge-groups.
__global__ __launch_bounds__(256) void k_aggxw(bf16* __restrict__ A2,
                                               const float* __restrict__ es,
                                               const float* __restrict__ ed,
                                               const int* __restrict__ rp,
                                               const int* __restrict__ ss)
{
    __shared__ float sal[4][4][65];
    __shared__ int   ssrc[4][64];

    const int w    = threadIdx.x >> 6;
    const int lane = threadIdx.x & 63;
    const int n    = blockIdx.x * 4 + w;
    if (n >= N_NODES) return;

    int r0 = clampi(rp[n], 0, E2);
    int r1 = clampi(rp[n + 1], r0, E2);
    const int deg = r1 - r0;

    f32x4 edn = *(const f32x4*)(ed + n * 4);

    // pass A: online softmax stats (max + denom), all 64 lanes over edges
    float mx[4] = {-1e30f, -1e30f, -1e30f, -1e30f};
    float sm[4] = {0.f, 0.f, 0.f, 0.f};
    for (int c0 = 0; c0 < deg; c0 += 64) {
        const int e = c0 + lane;
        const bool val = (e < deg);
        const int s = val ? clampi(ss[r0 + e], 0, N_NODES - 1) : 0;
        f32x4 esv = *(const f32x4*)(es + s * 4);
        float w4[4], mc[4];
#pragma unroll
        for (int h = 0; h < 4; ++h) {
            float v = esv[h] + edn[h];
            v = (v > 0.f) ? v : 0.2f * v;
            w4[h] = val ? v : -1e30f;
            mc[h] = w4[h];
        }
#pragma unroll
        for (int off = 32; off; off >>= 1)
#pragma unroll
            for (int h = 0; h < 4; ++h) mc[h] = fmaxf(mc[h], __shfl_xor(mc[h], off));
        float ps[4];
#pragma unroll
        for (int h = 0; h < 4; ++h) {
            float mn = fmaxf(mx[h], mc[h]);
            float f  = __expf(mx[h] - mn);
            ps[h] = __expf(w4[h] - mn);
            mx[h] = mn;
            sm[h] *= f;
        }
#pragma unroll
        for (int off = 32; off; off >>= 1)
#pragma unroll
            for (int h = 0; h < 4; ++h) ps[h] += __shfl_xor(ps[h], off);
#pragma unroll
        for (int h = 0; h < 4; ++h) sm[h] += ps[h];
    }
    float sinv[4];
#pragma unroll
    for (int h = 0; h < 4; ++h) sinv[h] = 1.f / fmaxf(sm[h], 1e-16f);

    // pass B: alpha fill + 8-edge-per-instruction gather
    const int g  = lane >> 3;          // edge slot 0..7
    const int cb = (lane & 7) * 8;     // channel block 0..56
    float acc[4][8];
#pragma unroll
    for (int h = 0; h < 4; ++h)
#pragma unroll
        for (int j = 0; j < 8; ++j) acc[h][j] = 0.f;

    for (int c0 = 0; c0 < deg; c0 += 64) {
        const int ce = min(64, deg - c0);
        const bool val = (lane < ce);
        const int e = c0 + lane;
        const int s = val ? clampi(ss[r0 + e], 0, N_NODES - 1) : 0;
        f32x4 esv = *(const f32x4*)(es + s * 4);
#pragma unroll
        for (int h = 0; h < 4; ++h) {
            float v = esv[h] + edn[h];
            v = (v > 0.f) ? v : 0.2f * v;
            sal[w][h][lane] = val ? __expf(v - mx[h]) * sinv[h] : 0.f;
        }
        ssrc[w][lane] = s;
        // wave-synchronous LDS RAW: same-wave ds ops execute in order.
        const int ce8 = (ce + 7) & ~7;
        for (int eb = 0; eb < ce8; eb += 8) {
            const int sg = ssrc[w][eb + g];
            bf16x8 xv = *(const bf16x8*)(A2 + (size_t)sg * KA + 256 + cb);
            float a[4];
#pragma unroll
            for (int h = 0; h < 4; ++h) a[h] = sal[w][h][eb + g];
#pragma unroll
            for (int h = 0; h < 4; ++h)
#pragma unroll
                for (int j = 0; j < 8; ++j) acc[h][j] += a[h] * (float)xv[j];
        }
    }

    // fold across the 8 edge-groups
#pragma unroll
    for (int off = 8; off <= 32; off <<= 1)
#pragma unroll
        for (int h = 0; h < 4; ++h)
#pragma unroll
            for (int j = 0; j < 8; ++j) acc[h][j] += __shfl_xor(acc[h][j], off);

    if (g < 4) {                       // lane group g writes head g
        bf16x8 ov;
#pragma unroll
        for (int j = 0; j < 8; ++j) {
            float v = (g == 0) ? acc[0][j]
                    : (g == 1) ? acc[1][j]
                    : (g == 2) ? acc[2][j] : acc[3][j];
            ov[j] = (bf16)v;
        }
        *(bf16x8*)(A2 + (size_t)n * KA + g * 64 + cb) = ov;
    }
}

// layers 2/3 logits on h (wave per node)
template <int H, int C>
__global__ __launch_bounds__(256) void k_logits(const bf16* __restrict__ G,
                                                const bf16* __restrict__ as_,
                                                const bf16* __restrict__ ad_,
                                                float* __restrict__ es, float* __restrict__ ed)
{
    const int wave = threadIdx.x >> 6;
    const int lane = threadIdx.x & 63;
    const int n = blockIdx.x * 4 + wave;
    if (n >= N_NODES) return;

#pragma unroll
    for (int h = 0; h < H; ++h) {
        float s = 0.f, d = 0.f;
        if constexpr (C == 256) {
            bf16x4 g  = *(const bf16x4*)(G + (size_t)n * SG + h * 256 + lane * 4);
            bf16x4 av = *(const bf16x4*)(as_ + h * 256 + lane * 4);
            bf16x4 dv = *(const bf16x4*)(ad_ + h * 256 + lane * 4);
#pragma unroll
            for (int j = 0; j < 4; ++j) {
                float gv = (float)g[j];
                s += gv * (float)av[j];
                d += gv * (float)dv[j];
            }
        } else {
            for (int c = lane; c < C; c += 64) {
                float hv = (float)G[(size_t)n * SG + h * C + c];
                s += hv * (float)as_[h * C + c];
                d += hv * (float)ad_[h * C + c];
            }
        }
#pragma unroll
        for (int off = 32; off; off >>= 1) {
            s += __shfl_xor(s, off);
            d += __shfl_xor(d, off);
        }
        if (lane == 0) { es[n * H + h] = s; ed[n * H + h] = d; }
    }
}

// R7: wave-per-node aggregate for layer 2 (H=4, C=256, D=1024).
__global__ __launch_bounds__(256) void k_aggw(const bf16* __restrict__ G,
                                              const bf16* __restrict__ S,
                                              const float* __restrict__ es,
                                              const float* __restrict__ ed,
                                              const int* __restrict__ rp,
                                              const int* __restrict__ ss,
                                              const bf16* __restrict__ bgat,
                                              const bf16* __restrict__ bskip,
                                              bf16* __restrict__ out, int sout)
{
    __shared__ float sal[4][4][65];    // [wave][head][edge] (+pad)
    __shared__ int   ssrc[4][64];

    const int w    = threadIdx.x >> 6;
    const int lane = threadIdx.x & 63;
    const int n    = blockIdx.x * 4 + w;
    if (n >= N_NODES) return;

    int r0 = clampi(rp[n], 0, E2);
    int r1 = clampi(rp[n + 1], r0, E2);
    const int deg = r1 - r0;

    f32x4 edn = *(const f32x4*)(ed + n * 4);

    // ---- pass A: online max+sum (replicated across lanes via all-reduce)
    float mx[4] = {-1e30f, -1e30f, -1e30f, -1e30f};
    float sm[4] = {0.f, 0.f, 0.f, 0.f};
    for (int c0 = 0; c0 < deg; c0 += 64) {
        const int e = c0 + lane;
        const bool val = (e < deg);
        const int s = val ? clampi(ss[r0 + e], 0, N_NODES - 1) : 0;
        f32x4 esv = *(const f32x4*)(es + s * 4);
        float w4[4], mc[4];
#pragma unroll
        for (int h = 0; h < 4; ++h) {
            float v = esv[h] + edn[h];
            v = (v > 0.f) ? v : 0.2f * v;
            w4[h] = val ? v : -1e30f;
            mc[h] = w4[h];
        }
#pragma unroll
        for (int off = 32; off; off >>= 1)
#pragma unroll
            for (int h = 0; h < 4; ++h) mc[h] = fmaxf(mc[h], __shfl_xor(mc[h], off));
        float ps[4];
#pragma unroll
        for (int h = 0; h < 4; ++h) {
            float mn = fmaxf(mx[h], mc[h]);
            float f  = __expf(mx[h] - mn);
            ps[h] = __expf(w4[h] - mn);
            mx[h] = mn;
            sm[h] *= f;
        }
#pragma unroll
        for (int off = 32; off; off >>= 1)
#pragma unroll
            for (int h = 0; h < 4; ++h) ps[h] += __shfl_xor(ps[h], off);
#pragma unroll
        for (int h = 0; h < 4; ++h) sm[h] += ps[h];
    }
    float sinv[4];
#pragma unroll
    for (int h = 0; h < 4; ++h) sinv[h] = 1.f / fmaxf(sm[h], 1e-16f);

    // ---- pass B: per-chunk alpha fill + gather
    const int myh  = lane >> 4;
    const int c0ch = lane * 16;
    float acc[16];
#pragma unroll
    for (int j = 0; j < 16; ++j) acc[j] = 0.f;

    for (int c0 = 0; c0 < deg; c0 += 64) {
        const int ce = min(64, deg - c0);
        const bool val = (lane < ce);
        const int e = c0 + lane;
        const int s = val ? clampi(ss[r0 + e], 0, N_NODES - 1) : 0;
        f32x4 esv = *(const f32x4*)(es + s * 4);
#pragma unroll
        for (int h = 0; h < 4; ++h) {
            float v = esv[h] + edn[h];
            v = (v > 0.f) ? v : 0.2f * v;
            sal[w][h][lane] = val ? __expf(v - mx[h]) * sinv[h] : 0.f;
        }
        ssrc[w][lane] = s;
        const int ce4 = (ce + 3) & ~3;
        for (int eb = 0; eb < ce4; eb += 4) {
            int sg[4]; float a[4];
#pragma unroll
            for (int p = 0; p < 4; ++p) {
                sg[p] = ssrc[w][eb + p];
                a[p]  = sal[w][myh][eb + p];
            }
            bf16x8 g0[4], g1[4];
#pragma unroll
            for (int p = 0; p < 4; ++p) {
                const bf16* gp = G + (size_t)sg[p] * SG + c0ch;
                g0[p] = *(const bf16x8*)gp;
                g1[p] = *(const bf16x8*)(gp + 8);
            }
#pragma unroll
            for (int p = 0; p < 4; ++p) {
#pragma unroll
                for (int j = 0; j < 8; ++j) acc[j]     += a[p] * (float)g0[p][j];
#pragma unroll
                for (int j = 0; j < 8; ++j) acc[j + 8] += a[p] * (float)g1[p][j];
            }
        }
    }

    // ---- epilogue: + bgat + skip + bskip, ELU, store 32B
    bf16x8 bg0 = *(const bf16x8*)(bgat + c0ch);
    bf16x8 bg1 = *(const bf16x8*)(bgat + c0ch + 8);
    bf16x8 sk0 = *(const bf16x8*)(S + (size_t)n * SG + c0ch);
    bf16x8 sk1 = *(const bf16x8*)(S + (size_t)n * SG + c0ch + 8);
    bf16x8 bs0 = *(const bf16x8*)(bskip + c0ch);
    bf16x8 bs1 = *(const bf16x8*)(bskip + c0ch + 8);
    bf16x8 ov0, ov1;
#pragma unroll
    for (int j = 0; j < 8; ++j) {
        float v = acc[j] + (float)bg0[j] + (float)sk0[j] + (float)bs0[j];
        v = (v > 0.f) ? v : (__expf(v) - 1.f);
        ov0[j] = (bf16)v;
        float u = acc[j + 8] + (float)bg1[j] + (float)sk1[j] + (float)bs1[j];
        u = (u > 0.f) ? u : (__expf(u) - 1.f);
        ov1[j] = (bf16)u;
    }
    *(bf16x8*)(out + (size_t)n * sout + c0ch)     = ov0;
    *(bf16x8*)(out + (size_t)n * sout + c0ch + 8) = ov1;
}

// R8: wave-per-node aggregate for layer 3 (H=6, C=121, MEAN over heads).
// Lane owns 12 consecutive channels of the 726-dim GAT row (3x bf16x4,
// 8B aligned); per-lane hA/hB head split (<=2 heads per 12-ch span).
// Zero barriers; wave-local LDS sfold[726] does the head-mean epilogue.
__global__ __launch_bounds__(256) void k_aggw3(const bf16* __restrict__ G,
                                               const bf16* __restrict__ S,
                                               const float* __restrict__ es,
                                               const float* __restrict__ ed,
                                               const int* __restrict__ rp,
                                               const int* __restrict__ ss,
                                               const bf16* __restrict__ bgat,
                                               const bf16* __restrict__ bskip,
                                               void* __restrict__ out, int sout,
                                               const int* __restrict__ flags)
{
    __shared__ float sal[4][6][65];
    __shared__ int   ssrc[4][64];
    __shared__ float sfold[4][728];

    const int w    = threadIdx.x >> 6;
    const int lane = threadIdx.x & 63;
    const int n    = blockIdx.x * 4 + w;
    if (n >= N_NODES) return;

    int r0 = clampi(rp[n], 0, E2);
    int r1 = clampi(rp[n + 1], r0, E2);
    const int deg = r1 - r0;

    float edn[6];
#pragma unroll
    for (int h = 0; h < 6; ++h) edn[h] = ed[n * 6 + h];

    // pass A: online softmax stats, 6 heads
    float mx[6], sm[6];
#pragma unroll
    for (int h = 0; h < 6; ++h) { mx[h] = -1e30f; sm[h] = 0.f; }
    for (int c0 = 0; c0 < deg; c0 += 64) {
        const int e = c0 + lane;
        const bool val = (e < deg);
        const int s = val ? clampi(ss[r0 + e], 0, N_NODES - 1) : 0;
        const float* ep = es + (size_t)s * 6;
        float w6[6], mc[6];
#pragma unroll
        for (int h = 0; h < 6; ++h) {
            float v = ep[h] + edn[h];
            v = (v > 0.f) ? v : 0.2f * v;
            w6[h] = val ? v : -1e30f;
            mc[h] = w6[h];
        }
#pragma unroll
        for (int off = 32; off; off >>= 1)
#pragma unroll
            for (int h = 0; h < 6; ++h) mc[h] = fmaxf(mc[h], __shfl_xor(mc[h], off));
        float ps[6];
#pragma unroll
        for (int h = 0; h < 6; ++h) {
            float mn = fmaxf(mx[h], mc[h]);
            float f  = __expf(mx[h] - mn);
            ps[h] = __expf(w6[h] - mn);
            mx[h] = mn;
            sm[h] *= f;
        }
#pragma unroll
        for (int off = 32; off; off >>= 1)
#pragma unroll
            for (int h = 0; h < 6; ++h) ps[h] += __shfl_xor(ps[h], off);
#pragma unroll
        for (int h = 0; h < 6; ++h) sm[h] += ps[h];
    }
    float sinv[6];
#pragma unroll
    for (int h = 0; h < 6; ++h) sinv[h] = 1.f / fmaxf(sm[h], 1e-16f);

    // pass B: lane owns 12 channels at c0ch; junk channels >=726 are
    // accumulated (in-bounds, finite: skip/pad region) but never written.
    const int c0ch = lane * 12;
    const int hA = min(c0ch / 121, 5);
    const int hB = min((c0ch + 11) / 121, 5);
    bool jA[12];
#pragma unroll
    for (int j = 0; j < 12; ++j) jA[j] = (min((c0ch + j) / 121, 5) == hA);

    float acc[12];
#pragma unroll
    for (int j = 0; j < 12; ++j) acc[j] = 0.f;

    for (int c0 = 0; c0 < deg; c0 += 64) {
        const int ce = min(64, deg - c0);
        const bool val = (lane < ce);
        const int e = c0 + lane;
        const int s = val ? clampi(ss[r0 + e], 0, N_NODES - 1) : 0;
        const float* ep = es + (size_t)s * 6;
#pragma unroll
        for (int h = 0; h < 6; ++h) {
            float v = ep[h] + edn[h];
            v = (v > 0.f) ? v : 0.2f * v;
            sal[w][h][lane] = val ? __expf(v - mx[h]) * sinv[h] : 0.f;
        }
        ssrc[w][lane] = s;
        const int ce4 = (ce + 3) & ~3;
        for (int eb = 0; eb < ce4; eb += 4) {
            int sg[4]; float aL[4], aH[4];
#pragma unroll
            for (int p = 0; p < 4; ++p) {
                sg[p] = ssrc[w][eb + p];
                aL[p] = sal[w][hA][eb + p];
                aH[p] = sal[w][hB][eb + p];
            }
#pragma unroll
            for (int p = 0; p < 4; ++p) {
                const bf16* gp = G + (size_t)sg[p] * SG + c0ch;
                bf16x4 g0 = *(const bf16x4*)gp;
                bf16x4 g1 = *(const bf16x4*)(gp + 4);
                bf16x4 g2 = *(const bf16x4*)(gp + 8);
#pragma unroll
                for (int j = 0; j < 4; ++j) acc[j]     += (jA[j]     ? aL[p] : aH[p]) * (float)g0[j];
#pragma unroll
                for (int j = 0; j < 4; ++j) acc[4 + j] += (jA[4 + j] ? aL[p] : aH[p]) * (float)g1[j];
#pragma unroll
                for (int j = 0; j < 4; ++j) acc[8 + j] += (jA[8 + j] ? aL[p] : aH[p]) * (float)g2[j];
            }
        }
    }

    // head-mean epilogue via wave-local LDS fold (wave-synchronous, in-order)
#pragma unroll
    for (int j = 0; j < 12; ++j) {
        int c = c0ch + j;
        if (c < 726) sfold[w][c] = acc[j];
    }
    const int outbf = flags[1];
    for (int c = lane; c < 121; c += 64) {
        float v = 0.f;
#pragma unroll
        for (int h = 0; h < 6; ++h) v += sfold[w][h * 121 + c];
        v *= (1.f / 6.f);
        v += (float)bgat[c] + (float)S[(size_t)n * SG + c] + (float)bskip[c];
        if (outbf) ((bf16*)out)[(size_t)n * sout + c] = (bf16)v;
        else       ((float*)out)[(size_t)n * sout + c] = v;
    }
}

// ----------------------------------------------------------------- launch ---
extern "C" void kernel_launch(void* const* d_in, const int* in_sizes, int n_in,
                              void* d_out, int out_size, void* d_ws, size_t ws_size,
                              hipStream_t stream)
{
    const void* x   = d_in[0];
    const int*  ei  = (const int*)d_in[1];
    const void* W1  = d_in[2];
    const void* Wl1 = d_in[6];
    const void* W2  = d_in[8];
    const void* Wl2 = d_in[12];
    const void* W3  = d_in[14];
    const void* Wl3 = d_in[18];

    P12 ps;
    ps.s[0] = d_in[3];  ps.s[1] = d_in[4];  ps.s[2] = d_in[5];  ps.s[3] = d_in[7];
    ps.s[4] = d_in[9];  ps.s[5] = d_in[10]; ps.s[6] = d_in[11]; ps.s[7] = d_in[13];
    ps.s[8] = d_in[15]; ps.s[9] = d_in[16]; ps.s[10] = d_in[17]; ps.s[11] = d_in[19];

    char* w = (char*)d_ws;
    auto alloc = [&](size_t bytes) {
        char* p = w;
        w += (bytes + 255) & ~(size_t)255;
        return p;
    };
    int*   flags = (int*)alloc(64);
    int*   cnt   = (int*)alloc((size_t)N_NODES * 4);
    int*   rp    = (int*)alloc((size_t)(N_NODES + 1) * 4);
    int*   cur   = (int*)alloc((size_t)N_NODES * 4);
    int*   ss    = (int*)alloc((size_t)E2 * 4);
    float* es    = (float*)alloc((size_t)N_NODES * 6 * 4);
    float* ed    = (float*)alloc((size_t)N_NODES * 6 * 4);
    bf16*  pool  = (bf16*)alloc((size_t)PO_END * 2);
    float* ws1   = (float*)alloc((size_t)64 * 4 * 4);
    float* wd1   = (float*)alloc((size_t)64 * 4 * 4);
    bf16*  bsum  = (bf16*)alloc((size_t)D1 * 2);
    bf16*  Bt    = (bf16*)alloc((size_t)NP12 * 1024 * 2);
    bf16*  X     = (bf16*)alloc((size_t)N_NODES * D1 * 2);   // x1/x2
    bf16*  WS    = (bf16*)alloc((size_t)N_NODES * SG * 2);   // GEMM out [gat|skip]
    bf16*  A2    = WS;   // layer-1 A'' [N x KA] aliases WS (dead during layer 1)

    k_detect<<<1, 64, 0, stream>>>(ei, (const unsigned short*)x, flags);

    hipMemsetAsync(cnt, 0, N_NODES * 4, stream);
    k_count<<<(E2 + 255) / 256, 256, 0, stream>>>(ei, cnt, flags);
    k_scan<<<1, 256, 0, stream>>>(cnt, rp, cur);
    k_fill<<<(E2 + 255) / 256, 256, 0, stream>>>(ei, cur, ss, flags);

    const dim3 blk(256);
    const int MT = (N_NODES + 127) / 128;   // 157

    // ---- layer 1: veca -> merged prep -> aggxw -> GEMM (128^2, K=320)
    k_veca<<<64, 256, 0, stream>>>(W1, ps.s[0], ps.s[1], ps.s[2], ps.s[3],
                                   ws1, wd1, bsum, flags);
    k_prep<<<PB_PADX + PB_WF1 + PB_PAR + PB_LOG1, 256, 0, stream>>>(
        x, W1, Wl1, ps, A2, Bt, pool, ws1, wd1, es, ed, flags);
    k_aggxw<<<N_NODES / 4, 256, 0, stream>>>(A2, es, ed, rp, ss);
    k_gemm<true><<<MT * (D1 / 128), blk, 0, stream>>>(A2, Bt, X, N_NODES, KA, KA, KA, D1,
                                                      MT, D1 / 128, bsum);   // x1 = ELU(...)

    // ---- layer 2: K=1024, out 2048 = [GAT 1024 | skip 1024]
    k_wcatT<<<dim3(16, NP12 / 64), blk, 0, stream>>>(W2, Wl2, Bt, 1024, 1024, 1024, flags);
    k_gemm<false><<<MT * (NP12 / 128), blk, 0, stream>>>(X, Bt, WS, N_NODES, 1024, 1024, 1024, SG,
                                                         MT, NP12 / 128, nullptr);
    k_logits<4, 256><<<N_NODES / 4, 256, 0, stream>>>(WS, pool + PO_A2S, pool + PO_A2D, es, ed);
    k_aggw<<<N_NODES / 4, 256, 0, stream>>>(
        WS, WS + D1, es, ed, rp, ss, pool + PO_B2, pool + PO_BL2, X, D1);

    // ---- layer 3: K=1024, out 896 = [GAT 726 | skip 121 | pad]
    k_wcatT<<<dim3(16, NP3 / 64), blk, 0, stream>>>(W3, Wl3, Bt, 726, 726, 121, flags);
    k_gemm<false><<<MT * (NP3 / 128), blk, 0, stream>>>(X, Bt, WS, N_NODES, 1024, 1024, 1024, SG,
                                                        MT, NP3 / 128, nullptr);
    k_logits<6, 121><<<N_NODES / 4, 256, 0, stream>>>(WS, pool + PO_A3S, pool + PO_A3D, es, ed);
    k_aggw3<<<N_NODES / 4, 256, 0, stream>>>(
        WS, WS + 726, es, ed, rp, ss, pool + PO_B3, pool + PO_BL3, d_out, 121, flags);
}